// Round 1
// baseline (529.868 us; speedup 1.0000x reference)
//
#include <hip/hip_runtime.h>
#include <math.h>

#define T_ 2048
#define H_ 16

// ---------------- RMSNorm: x = states * rsqrt(mean(states^2)+eps) * ln_w ----------------
__global__ __launch_bounds__(256) void rmsnorm_kernel(
    const float* __restrict__ states, const float* __restrict__ ln_w,
    float* __restrict__ x) {
  const int row = blockIdx.x;  // b*T + t
  const int tid = threadIdx.x;
  const float4 v = ((const float4*)(states + (size_t)row * 1024))[tid];
  float ss = v.x * v.x + v.y * v.y + v.z * v.z + v.w * v.w;
#pragma unroll
  for (int off = 32; off >= 1; off >>= 1) ss += __shfl_xor(ss, off);
  __shared__ float red[4];
  if ((tid & 63) == 0) red[tid >> 6] = ss;
  __syncthreads();
  const float tot = red[0] + red[1] + red[2] + red[3];
  const float scale = rsqrtf(tot * (1.0f / 1024.0f) + 1.1920928955078125e-07f);
  const float4 w = ((const float4*)ln_w)[tid];
  float4 o;
  o.x = v.x * scale * w.x;
  o.y = v.y * scale * w.y;
  o.z = v.z * scale * w.z;
  o.w = v.w * scale * w.w;
  ((float4*)(x + (size_t)row * 1024))[tid] = o;
}

// ---------------- time features: t_q[t,h,2Dt], t_k[t,h,2Dt] ----------------
__global__ __launch_bounds__(256) void time_kernel(
    const float* __restrict__ angles, const float* __restrict__ delta,
    float* __restrict__ tq, float* __restrict__ tk) {
  const int gid = blockIdx.x * 256 + threadIdx.x;  // exactly T*H*32 threads
  const int j = gid & 31;
  const int h = (gid >> 5) & 15;
  const int t = gid >> 9;
  const float th = angles[j];
  const float aq = ((float)t + delta[h]) * th;
  const float ak = (float)t * th;
  float sq, cq, sk, ck;
  sincosf(aq, &sq, &cq);
  sincosf(ak, &sk, &ck);
  const size_t base = ((size_t)t * H_ + h) * 64;
  tq[base + j] = (cq + sq) * 0.125f;
  tq[base + 32 + j] = (cq - sq) * 0.125f;
  tk[base + j] = (ck + sk) * 0.125f;
  tk[base + 32 + j] = (ck - sk) * 0.125f;
}

// ---------------- fp32 NT GEMM: C[i,j] = sum_k A[i,k]*B[j,k] + bias[j] ----------------
// tile 128x64, BK=16, 256 threads, 8x4 microtile per thread.
#define BM 128
#define BN 64
#define BK 16

__device__ __forceinline__ void gemm_body(
    const float* __restrict__ A, int lda, const float* __restrict__ Bm, int ldb,
    const float* __restrict__ bias, float* __restrict__ C, int ldc, int K,
    int row0, int col0) {
  __shared__ float As[BK][BM + 4];
  __shared__ float Bs[BK][BN + 4];
  const int t = threadIdx.x;
  const int tx = t & 15, ty = t >> 4;
  const int lr = t >> 2;        // 0..63
  const int lk = (t & 3) * 4;   // 0,4,8,12
  float acc[8][4] = {};
  for (int k0 = 0; k0 < K; k0 += BK) {
    const float4 a0 = *(const float4*)(A + (size_t)(row0 + lr) * lda + k0 + lk);
    const float4 a1 = *(const float4*)(A + (size_t)(row0 + lr + 64) * lda + k0 + lk);
    const float4 b0 = *(const float4*)(Bm + (size_t)(col0 + lr) * ldb + k0 + lk);
    As[lk + 0][lr] = a0.x; As[lk + 1][lr] = a0.y; As[lk + 2][lr] = a0.z; As[lk + 3][lr] = a0.w;
    As[lk + 0][lr + 64] = a1.x; As[lk + 1][lr + 64] = a1.y; As[lk + 2][lr + 64] = a1.z; As[lk + 3][lr + 64] = a1.w;
    Bs[lk + 0][lr] = b0.x; Bs[lk + 1][lr] = b0.y; Bs[lk + 2][lr] = b0.z; Bs[lk + 3][lr] = b0.w;
    __syncthreads();
#pragma unroll
    for (int kk = 0; kk < BK; ++kk) {
      const float4 aA = *(const float4*)&As[kk][ty * 8];
      const float4 aB = *(const float4*)&As[kk][ty * 8 + 4];
      const float4 bb = *(const float4*)&Bs[kk][tx * 4];
      const float a[8] = {aA.x, aA.y, aA.z, aA.w, aB.x, aB.y, aB.z, aB.w};
      const float b[4] = {bb.x, bb.y, bb.z, bb.w};
#pragma unroll
      for (int i = 0; i < 8; ++i)
#pragma unroll
        for (int jj = 0; jj < 4; ++jj) acc[i][jj] = fmaf(a[i], b[jj], acc[i][jj]);
    }
    __syncthreads();
  }
  float4 b4 = make_float4(0.f, 0.f, 0.f, 0.f);
  if (bias) b4 = *(const float4*)(bias + col0 + tx * 4);
#pragma unroll
  for (int i = 0; i < 8; ++i) {
    float4 o;
    o.x = acc[i][0] + b4.x;
    o.y = acc[i][1] + b4.y;
    o.z = acc[i][2] + b4.z;
    o.w = acc[i][3] + b4.w;
    *(float4*)(C + (size_t)(row0 + ty * 8 + i) * ldc + col0 + tx * 4) = o;
  }
}

__global__ __launch_bounds__(256) void gemm_nt(
    const float* __restrict__ A, int lda, const float* __restrict__ Bm, int ldb,
    const float* __restrict__ bias, float* __restrict__ C, int ldc, int K) {
  gemm_body(A, lda, Bm, ldb, bias, C, ldc, K, blockIdx.y * BM, blockIdx.x * BN);
}

// loading[b,:,h,:] (2048x64) = tq[:,h,:] (2048x64) @ Mt[b,h] (B-operand: Mt[d,e])
__global__ __launch_bounds__(256) void loading_gemm(
    const float* __restrict__ tq, const float* __restrict__ Mt,
    float* __restrict__ loading) {
  const int bh = blockIdx.y;
  const int b = bh >> 4, h = bh & 15;
  gemm_body(tq + h * 64, 1024, Mt + (size_t)bh * 4096, 64, nullptr,
            loading + (size_t)b * T_ * 1024 + h * 64, 1024, 64,
            blockIdx.x * BM, 0);
}

// ---------------- kv = softmax_head(k * mask) * v  (in-place into k) ----------------
__global__ __launch_bounds__(256) void kv_kernel(
    float* __restrict__ k, const float* __restrict__ v,
    const int* __restrict__ mask) {
  const int g = blockIdx.x * 256 + threadIdx.x;
  const int lane = g & 63;
  const int w = g >> 6;      // (b*T+t)*H + h
  const int h = w & 15;
  const int row = w >> 4;    // b*T + t
  const float m = (float)mask[row];
  const size_t idx = (size_t)row * 1024 + h * 64 + lane;
  const float kf = k[idx] * m;
  float mx = kf;
#pragma unroll
  for (int off = 32; off >= 1; off >>= 1) mx = fmaxf(mx, __shfl_xor(mx, off));
  const float e = expf(kf - mx);
  float s = e;
#pragma unroll
  for (int off = 32; off >= 1; off >>= 1) s += __shfl_xor(s, off);
  k[idx] = (e / s) * v[idx];
}

// ---------------- Mt[b,h][d,e] = sum_l kv[b,l,h,d] * tk[l,h,e] ----------------
// grid = (B*H)*8 chunks of 256 l-values; accumulate via fp32 atomics.
__global__ __launch_bounds__(256) void mt_kernel(
    const float* __restrict__ kv, const float* __restrict__ tk,
    float* __restrict__ Mt) {
  const int chunk = blockIdx.x & 7;
  const int bh = blockIdx.x >> 3;
  const int h = bh & 15, b = bh >> 4;
  const int tid = threadIdx.x;
  const int dg = tid & 15, eg = tid >> 4;
  __shared__ float tks[32][64];
  __shared__ float kvs[32][64];
  float acc[4][4] = {};
  const int l0 = chunk * 256;
  for (int ls = 0; ls < 256; ls += 32) {
    const int lr = tid >> 3;
    const int cc = (tid & 7) * 8;
    const int l = l0 + ls + lr;
    const float* tkp = tk + ((size_t)l * H_ + h) * 64 + cc;
    const float* kvp = kv + ((size_t)(b * T_ + l)) * 1024 + h * 64 + cc;
    *(float4*)&tks[lr][cc] = *(const float4*)tkp;
    *(float4*)&tks[lr][cc + 4] = *(const float4*)(tkp + 4);
    *(float4*)&kvs[lr][cc] = *(const float4*)kvp;
    *(float4*)&kvs[lr][cc + 4] = *(const float4*)(kvp + 4);
    __syncthreads();
#pragma unroll
    for (int l2 = 0; l2 < 32; ++l2) {
      const float4 ev = *(const float4*)&tks[l2][eg * 4];
      const float4 dv = *(const float4*)&kvs[l2][dg * 4];
      const float e4[4] = {ev.x, ev.y, ev.z, ev.w};
      const float d4[4] = {dv.x, dv.y, dv.z, dv.w};
#pragma unroll
      for (int i = 0; i < 4; ++i)
#pragma unroll
        for (int j = 0; j < 4; ++j) acc[i][j] = fmaf(e4[i], d4[j], acc[i][j]);
    }
    __syncthreads();
  }
  float* Mbh = Mt + (size_t)bh * 4096;
#pragma unroll
  for (int i = 0; i < 4; ++i)
#pragma unroll
    for (int j = 0; j < 4; ++j)
      atomicAdd(&Mbh[(size_t)(dg * 4 + j) * 64 + (eg * 4 + i)], acc[i][j]);
}

extern "C" void kernel_launch(void* const* d_in, const int* in_sizes, int n_in,
                              void* d_out, int out_size, void* d_ws, size_t ws_size,
                              hipStream_t stream) {
  (void)in_sizes; (void)n_in; (void)out_size; (void)ws_size;
  const float* states = (const float*)d_in[0];
  const int* mask = (const int*)d_in[1];
  const float* ln_w = (const float*)d_in[2];
  const float* angles = (const float*)d_in[3];
  const float* delta = (const float*)d_in[4];
  // d_in[5]=Wq, d_in[6]=q_bias are provably unused: softmax row-sums are 1.
  const float* Wk = (const float*)d_in[7];
  const float* bk = (const float*)d_in[8];
  const float* Wv = (const float*)d_in[9];
  const float* bv = (const float*)d_in[10];
  const float* Wo = (const float*)d_in[11];
  const float* bo = (const float*)d_in[12];
  float* out = (float*)d_out;

  float* ws = (float*)d_ws;
  float* x = ws;                  // [4096,1024]  (reused as 'loading' later)
  float* kb = ws + 4194304;       // [4096,1024]  k -> kv in place
  float* vb = ws + 8388608;       // [4096,1024]
  float* tq = ws + 12582912;      // [2048,16,64]
  float* tk = ws + 14680064;      // [2048,16,64]
  float* Mt = ws + 16777216;      // [32][64][64]
  float* loading = x;

  rmsnorm_kernel<<<4096, 256, 0, stream>>>(states, ln_w, x);
  time_kernel<<<4096, 256, 0, stream>>>(angles, delta, tq, tk);
  gemm_nt<<<dim3(16, 32), 256, 0, stream>>>(x, 1024, Wk, 1024, bk, kb, 1024, 1024);
  gemm_nt<<<dim3(16, 32), 256, 0, stream>>>(x, 1024, Wv, 1024, bv, vb, 1024, 1024);
  kv_kernel<<<16384, 256, 0, stream>>>(kb, vb, mask);
  hipMemsetAsync(Mt, 0, 131072 * sizeof(float), stream);
  mt_kernel<<<256, 256, 0, stream>>>(kb, tk, Mt);
  loading_gemm<<<dim3(16, 32), 256, 0, stream>>>(tq, Mt, loading);
  gemm_nt<<<dim3(16, 32), 256, 0, stream>>>(loading, 1024, Wo, 1024, bo, out, 1024, 1024);
}

// Round 2
// 210.696 us; speedup vs baseline: 2.5148x; 2.5148x over previous
//
#include <hip/hip_runtime.h>
#include <math.h>

#define T_ 2048
#define H_ 16

typedef __attribute__((ext_vector_type(8))) short bfx8;   // 8 bf16 = 4 VGPRs
typedef __attribute__((ext_vector_type(4))) float f32x4;  // MFMA accumulator

__device__ __forceinline__ short f2bf(float f) {
  union { float f; unsigned u; } x; x.f = f;
  unsigned r = (x.u + 0x7FFFu + ((x.u >> 16) & 1u)) >> 16;  // RNE
  return (short)r;
}

#define GLD_LDS(g, l) \
  __builtin_amdgcn_global_load_lds( \
      (const __attribute__((address_space(1))) void*)(g), \
      (__attribute__((address_space(3))) void*)(l), 16, 0, 0)

// ---------------- RMSNorm -> bf16 x ----------------
__global__ __launch_bounds__(256) void rmsnorm_kernel(
    const float* __restrict__ states, const float* __restrict__ ln_w,
    short* __restrict__ xb) {
  const int row = blockIdx.x;  // b*T + t
  const int tid = threadIdx.x;
  const float4 v = ((const float4*)(states + (size_t)row * 1024))[tid];
  float ss = v.x * v.x + v.y * v.y + v.z * v.z + v.w * v.w;
#pragma unroll
  for (int off = 32; off >= 1; off >>= 1) ss += __shfl_xor(ss, off);
  __shared__ float red[4];
  if ((tid & 63) == 0) red[tid >> 6] = ss;
  __syncthreads();
  const float tot = red[0] + red[1] + red[2] + red[3];
  const float scale = rsqrtf(tot * (1.0f / 1024.0f) + 1.1920928955078125e-07f);
  const float4 w = ((const float4*)ln_w)[tid];
  short4 o;
  o.x = f2bf(v.x * scale * w.x);
  o.y = f2bf(v.y * scale * w.y);
  o.z = f2bf(v.z * scale * w.z);
  o.w = f2bf(v.w * scale * w.w);
  ((short4*)(xb + (size_t)row * 1024))[tid] = o;
}

// ---------------- fp32 weights -> bf16 (3 x 1M elements) ----------------
__global__ __launch_bounds__(256) void cvt3_kernel(
    const float* __restrict__ w0, const float* __restrict__ w1,
    const float* __restrict__ w2, short* __restrict__ o0,
    short* __restrict__ o1, short* __restrict__ o2) {
  const int i = blockIdx.x * 256 + threadIdx.x;  // 0 .. 3*2^18-1 float4s
  const int which = i >> 18;
  const int idx = i & 262143;
  const float* s = (which == 0) ? w0 : (which == 1) ? w1 : w2;
  short* d = (which == 0) ? o0 : (which == 1) ? o1 : o2;
  const float4 v = ((const float4*)s)[idx];
  short4 r;
  r.x = f2bf(v.x); r.y = f2bf(v.y); r.z = f2bf(v.z); r.w = f2bf(v.w);
  ((short4*)d)[idx] = r;
}

// ---------------- time features ----------------
__global__ __launch_bounds__(256) void time_kernel(
    const float* __restrict__ angles, const float* __restrict__ delta,
    float* __restrict__ tq, float* __restrict__ tk) {
  const int gid = blockIdx.x * 256 + threadIdx.x;
  const int j = gid & 31;
  const int h = (gid >> 5) & 15;
  const int t = gid >> 9;
  const float th = angles[j];
  const float aq = ((float)t + delta[h]) * th;
  const float ak = (float)t * th;
  float sq, cq, sk, ck;
  sincosf(aq, &sq, &cq);
  sincosf(ak, &sk, &ck);
  const size_t base = ((size_t)t * H_ + h) * 64;
  tq[base + j] = (cq + sq) * 0.125f;
  tq[base + 32 + j] = (cq - sq) * 0.125f;
  tk[base + j] = (ck + sk) * 0.125f;
  tk[base + 32 + j] = (ck - sk) * 0.125f;
}

// ---------------- bf16 MFMA NT GEMM body: C[i,j] = sum_k A[i,k]*B[j,k] + bias[j]
// 128x128 block tile, BK=32, 256 threads (4 waves, each 64x64), 16x16x32 MFMA.
__device__ __forceinline__ void gemm_bf16_body(
    const short* __restrict__ A, const short* __restrict__ B,
    const float* __restrict__ bias, float* __restrict__ C,
    const int K, const int ldc, const int row0, const int col0) {
  __shared__ short As[128][32];
  __shared__ short Bs[128][32];
  const int t = threadIdx.x;
  const int lane = t & 63;
  const int wv = t >> 6;
  const int wm = (wv & 1) * 64, wn = (wv >> 1) * 64;
  const int lrow = lane & 15;
  const int kg = (lane >> 4) * 8;
  const int srow = t >> 2;        // 0..63
  const int skb = (t & 3) * 8;    // k offset in shorts (16B)
  const short* ga = A + (size_t)(row0 + srow) * K + skb;
  const short* gb = B + (size_t)(col0 + srow) * K + skb;

  f32x4 acc[4][4] = {};
  for (int k0 = 0; k0 < K; k0 += 32) {
    GLD_LDS(ga + k0, &As[srow][skb]);
    GLD_LDS(ga + (size_t)64 * K + k0, &As[64 + srow][skb]);
    GLD_LDS(gb + k0, &Bs[srow][skb]);
    GLD_LDS(gb + (size_t)64 * K + k0, &Bs[64 + srow][skb]);
    __syncthreads();
    bfx8 af[4], bf_[4];
#pragma unroll
    for (int i = 0; i < 4; ++i) af[i] = *(const bfx8*)&As[wm + i * 16 + lrow][kg];
#pragma unroll
    for (int j = 0; j < 4; ++j) bf_[j] = *(const bfx8*)&Bs[wn + j * 16 + lrow][kg];
#pragma unroll
    for (int i = 0; i < 4; ++i)
#pragma unroll
      for (int j = 0; j < 4; ++j)
        acc[i][j] = __builtin_amdgcn_mfma_f32_16x16x32_bf16(af[i], bf_[j], acc[i][j], 0, 0, 0);
    __syncthreads();
  }
  // C/D layout: col = lane&15, row = (lane>>4)*4 + reg
  const int orow = row0 + wm + (lane >> 4) * 4;
  const int ocol = col0 + wn + lrow;
#pragma unroll
  for (int j = 0; j < 4; ++j) {
    const int c = ocol + j * 16;
    const float bb = bias ? bias[c] : 0.0f;
#pragma unroll
    for (int i = 0; i < 4; ++i) {
      const int r = orow + i * 16;
#pragma unroll
      for (int rr = 0; rr < 4; ++rr)
        C[(size_t)(r + rr) * ldc + c] = acc[i][j][rr] + bb;
    }
  }
}

// fused K+V GEMM: x[4096,1024]bf16 x {Wk,Wv}[1024,1024]bf16 -> kb, vb fp32
__global__ __launch_bounds__(256) void kvgemm_kernel(
    const short* __restrict__ x, const short* __restrict__ Wkb,
    const short* __restrict__ Wvb, const float* __restrict__ bk,
    const float* __restrict__ bv, float* __restrict__ kout,
    float* __restrict__ vout) {
  const int nt = blockIdx.x;  // 0..15
  const bool isK = nt < 8;
  gemm_bf16_body(x, isK ? Wkb : Wvb, isK ? bk : bv, isK ? kout : vout,
                 1024, 1024, blockIdx.y * 128, (nt & 7) * 128);
}

// final GEMM: loading[4096,1024]bf16 x Wo[1024,1024]bf16 + bo -> out fp32
__global__ __launch_bounds__(256) void ogemm_kernel(
    const short* __restrict__ ld, const short* __restrict__ Wob,
    const float* __restrict__ bo, float* __restrict__ out) {
  gemm_bf16_body(ld, Wob, bo, out, 1024, 1024, blockIdx.y * 128,
                 blockIdx.x * 128);
}

// ---------------- fp32 NT GEMM (small, loading path), bf16 output ----------------
#define BM 128
#define BN 64
#define BK 16
__device__ __forceinline__ void gemm_body_f32(
    const float* __restrict__ A, int lda, const float* __restrict__ Bm, int ldb,
    short* __restrict__ C, int ldc, int K, int row0, int col0) {
  __shared__ float As[BK][BM + 4];
  __shared__ float Bs[BK][BN + 4];
  const int t = threadIdx.x;
  const int tx = t & 15, ty = t >> 4;
  const int lr = t >> 2;
  const int lk = (t & 3) * 4;
  float acc[8][4] = {};
  for (int k0 = 0; k0 < K; k0 += BK) {
    const float4 a0 = *(const float4*)(A + (size_t)(row0 + lr) * lda + k0 + lk);
    const float4 a1 = *(const float4*)(A + (size_t)(row0 + lr + 64) * lda + k0 + lk);
    const float4 b0 = *(const float4*)(Bm + (size_t)(col0 + lr) * ldb + k0 + lk);
    As[lk + 0][lr] = a0.x; As[lk + 1][lr] = a0.y; As[lk + 2][lr] = a0.z; As[lk + 3][lr] = a0.w;
    As[lk + 0][lr + 64] = a1.x; As[lk + 1][lr + 64] = a1.y; As[lk + 2][lr + 64] = a1.z; As[lk + 3][lr + 64] = a1.w;
    Bs[lk + 0][lr] = b0.x; Bs[lk + 1][lr] = b0.y; Bs[lk + 2][lr] = b0.z; Bs[lk + 3][lr] = b0.w;
    __syncthreads();
#pragma unroll
    for (int kk = 0; kk < BK; ++kk) {
      const float4 aA = *(const float4*)&As[kk][ty * 8];
      const float4 aB = *(const float4*)&As[kk][ty * 8 + 4];
      const float4 bb = *(const float4*)&Bs[kk][tx * 4];
      const float a[8] = {aA.x, aA.y, aA.z, aA.w, aB.x, aB.y, aB.z, aB.w};
      const float b[4] = {bb.x, bb.y, bb.z, bb.w};
#pragma unroll
      for (int i = 0; i < 8; ++i)
#pragma unroll
        for (int jj = 0; jj < 4; ++jj) acc[i][jj] = fmaf(a[i], b[jj], acc[i][jj]);
    }
    __syncthreads();
  }
#pragma unroll
  for (int i = 0; i < 8; ++i) {
    short4 o;
    o.x = f2bf(acc[i][0]); o.y = f2bf(acc[i][1]);
    o.z = f2bf(acc[i][2]); o.w = f2bf(acc[i][3]);
    *(short4*)(C + (size_t)(row0 + ty * 8 + i) * ldc + col0 + tx * 4) = o;
  }
}

// loading[b,:,h,:] = tq[:,h,:] @ Mt[b,h]^T-ish (NT with B=Mt[d][e]) -> bf16
__global__ __launch_bounds__(256) void loading_gemm(
    const float* __restrict__ tq, const float* __restrict__ Mt,
    short* __restrict__ loading) {
  const int bh = blockIdx.y;
  const int b = bh >> 4, h = bh & 15;
  gemm_body_f32(tq + h * 64, 1024, Mt + (size_t)bh * 4096,
                64, loading + (size_t)b * T_ * 1024 + h * 64, 1024, 64,
                blockIdx.x * BM, 0);
}

// ---------------- kv = softmax_head(k * mask) * v  (in-place into k) ----------------
__global__ __launch_bounds__(256) void kv_kernel(
    float* __restrict__ k, const float* __restrict__ v,
    const int* __restrict__ mask) {
  const int g = blockIdx.x * 256 + threadIdx.x;
  const int lane = g & 63;
  const int w = g >> 6;
  const int h = w & 15;
  const int row = w >> 4;
  const float m = (float)mask[row];
  const size_t idx = (size_t)row * 1024 + h * 64 + lane;
  const float kf = k[idx] * m;
  float mx = kf;
#pragma unroll
  for (int off = 32; off >= 1; off >>= 1) mx = fmaxf(mx, __shfl_xor(mx, off));
  const float e = expf(kf - mx);
  float s = e;
#pragma unroll
  for (int off = 32; off >= 1; off >>= 1) s += __shfl_xor(s, off);
  k[idx] = (e / s) * v[idx];
}

// ---------------- Mt[b,h][d,e] = sum_l kv[b,l,h,d] * tk[l,h,e] ----------------
__global__ __launch_bounds__(256) void mt_kernel(
    const float* __restrict__ kv, const float* __restrict__ tk,
    float* __restrict__ Mt) {
  const int chunk = blockIdx.x & 7;
  const int bh = blockIdx.x >> 3;
  const int h = bh & 15, b = bh >> 4;
  const int tid = threadIdx.x;
  const int dg = tid & 15, eg = tid >> 4;
  __shared__ float tks[32][64];
  __shared__ float kvs[32][64];
  float acc[4][4] = {};
  const int l0 = chunk * 256;
  for (int ls = 0; ls < 256; ls += 32) {
    const int lr = tid >> 3;
    const int cc = (tid & 7) * 8;
    const int l = l0 + ls + lr;
    const float* tkp = tk + ((size_t)l * H_ + h) * 64 + cc;
    const float* kvp = kv + ((size_t)(b * T_ + l)) * 1024 + h * 64 + cc;
    *(float4*)&tks[lr][cc] = *(const float4*)tkp;
    *(float4*)&tks[lr][cc + 4] = *(const float4*)(tkp + 4);
    *(float4*)&kvs[lr][cc] = *(const float4*)kvp;
    *(float4*)&kvs[lr][cc + 4] = *(const float4*)(kvp + 4);
    __syncthreads();
#pragma unroll
    for (int l2 = 0; l2 < 32; ++l2) {
      const float4 ev = *(const float4*)&tks[l2][eg * 4];
      const float4 dv = *(const float4*)&kvs[l2][dg * 4];
      const float e4[4] = {ev.x, ev.y, ev.z, ev.w};
      const float d4[4] = {dv.x, dv.y, dv.z, dv.w};
#pragma unroll
      for (int i = 0; i < 4; ++i)
#pragma unroll
        for (int j = 0; j < 4; ++j) acc[i][j] = fmaf(e4[i], d4[j], acc[i][j]);
    }
    __syncthreads();
  }
  float* Mbh = Mt + (size_t)bh * 4096;
#pragma unroll
  for (int i = 0; i < 4; ++i)
#pragma unroll
    for (int j = 0; j < 4; ++j)
      atomicAdd(&Mbh[(size_t)(dg * 4 + j) * 64 + (eg * 4 + i)], acc[i][j]);
}

extern "C" void kernel_launch(void* const* d_in, const int* in_sizes, int n_in,
                              void* d_out, int out_size, void* d_ws, size_t ws_size,
                              hipStream_t stream) {
  (void)in_sizes; (void)n_in; (void)out_size; (void)ws_size;
  const float* states = (const float*)d_in[0];
  const int* mask = (const int*)d_in[1];
  const float* ln_w = (const float*)d_in[2];
  const float* angles = (const float*)d_in[3];
  const float* delta = (const float*)d_in[4];
  // d_in[5]=Wq, d_in[6]=q_bias provably unused (softmax row-sums are 1).
  const float* Wk = (const float*)d_in[7];
  const float* bk = (const float*)d_in[8];
  const float* Wv = (const float*)d_in[9];
  const float* bv = (const float*)d_in[10];
  const float* Wo = (const float*)d_in[11];
  const float* bo = (const float*)d_in[12];
  float* out = (float*)d_out;

  float* ws = (float*)d_ws;
  float* kb = ws;                         // [4096,1024] f32, k -> kv in place
  float* vb = ws + 4194304;               // [4096,1024] f32; later reused as bf16 'loading'
  float* tq = ws + 8388608;               // [2048,16,64] f32
  float* tk = ws + 10485760;              // [2048,16,64] f32
  float* Mt = ws + 12582912;              // [32][64][64] f32
  short* xb = (short*)(ws + 12713984);    // [4096,1024] bf16
  short* Wkb = (short*)(ws + 14811136);   // [1024,1024] bf16
  short* Wvb = (short*)(ws + 15335424);
  short* Wob = (short*)(ws + 15859712);
  short* loading = (short*)vb;            // [4096,1024] bf16 (vb dead by then)

  cvt3_kernel<<<3072, 256, 0, stream>>>(Wk, Wv, Wo, Wkb, Wvb, Wob);
  rmsnorm_kernel<<<4096, 256, 0, stream>>>(states, ln_w, xb);
  time_kernel<<<4096, 256, 0, stream>>>(angles, delta, tq, tk);
  kvgemm_kernel<<<dim3(16, 32), 256, 0, stream>>>(xb, Wkb, Wvb, bk, bv, kb, vb);
  kv_kernel<<<16384, 256, 0, stream>>>(kb, vb, mask);
  hipMemsetAsync(Mt, 0, 131072 * sizeof(float), stream);
  mt_kernel<<<256, 256, 0, stream>>>(kb, tk, Mt);
  loading_gemm<<<dim3(16, 32), 256, 0, stream>>>(tq, Mt, loading);
  ogemm_kernel<<<dim3(8, 32), 256, 0, stream>>>(loading, Wob, bo, out);
}

// Round 4
// 185.710 us; speedup vs baseline: 2.8532x; 1.1345x over previous
//
#include <hip/hip_runtime.h>
#include <math.h>

#define T_ 2048
#define H_ 16

typedef __attribute__((ext_vector_type(8))) short bfx8;   // 8 bf16 = 4 VGPRs
typedef __attribute__((ext_vector_type(4))) float f32x4;  // MFMA accumulator

__device__ __forceinline__ short f2bf(float f) {
  union { float f; unsigned u; } x; x.f = f;
  unsigned r = (x.u + 0x7FFFu + ((x.u >> 16) & 1u)) >> 16;  // RNE
  return (short)r;
}
__device__ __forceinline__ float bf2f(short s) {
  union { unsigned u; float f; } x;
  x.u = ((unsigned)(unsigned short)s) << 16;
  return x.f;
}

#define GLD_LDS(g, l) \
  __builtin_amdgcn_global_load_lds( \
      (const __attribute__((address_space(1))) void*)(g), \
      (__attribute__((address_space(3))) void*)(l), 16, 0, 0)

// ---------------- RMSNorm -> bf16 x ----------------
__global__ __launch_bounds__(256) void rmsnorm_kernel(
    const float* __restrict__ states, const float* __restrict__ ln_w,
    short* __restrict__ xb) {
  const int row = blockIdx.x;
  const int tid = threadIdx.x;
  const float4 v = ((const float4*)(states + (size_t)row * 1024))[tid];
  float ss = v.x * v.x + v.y * v.y + v.z * v.z + v.w * v.w;
#pragma unroll
  for (int off = 32; off >= 1; off >>= 1) ss += __shfl_xor(ss, off);
  __shared__ float red[4];
  if ((tid & 63) == 0) red[tid >> 6] = ss;
  __syncthreads();
  const float tot = red[0] + red[1] + red[2] + red[3];
  const float scale = rsqrtf(tot * (1.0f / 1024.0f) + 1.1920928955078125e-07f);
  const float4 w = ((const float4*)ln_w)[tid];
  short4 o;
  o.x = f2bf(v.x * scale * w.x);
  o.y = f2bf(v.y * scale * w.y);
  o.z = f2bf(v.z * scale * w.z);
  o.w = f2bf(v.w * scale * w.w);
  ((short4*)(xb + (size_t)row * 1024))[tid] = o;
}

// ---------------- prep: weight cvt + tq (bf16, [t][h*64+e]) + tkT (bf16, [h][e][l])
__global__ __launch_bounds__(256) void prep_kernel(
    const float* __restrict__ Wk, const float* __restrict__ Wv,
    const float* __restrict__ Wo, const float* __restrict__ angles,
    const float* __restrict__ delta, short* __restrict__ Wkb,
    short* __restrict__ Wvb, short* __restrict__ Wob, short* __restrict__ tq,
    short* __restrict__ tkT) {
  const int blk = blockIdx.x;
  if (blk < 3072) {  // weight conversion: 3 x 2^18 float4s
    const int i = blk * 256 + threadIdx.x;
    const int which = i >> 18;
    const int idx = i & 262143;
    const float* s = (which == 0) ? Wk : (which == 1) ? Wv : Wo;
    short* d = (which == 0) ? Wkb : (which == 1) ? Wvb : Wob;
    const float4 v = ((const float4*)s)[idx];
    short4 r;
    r.x = f2bf(v.x); r.y = f2bf(v.y); r.z = f2bf(v.z); r.w = f2bf(v.w);
    ((short4*)d)[idx] = r;
  } else if (blk < 3072 + 4096) {  // tq: T*H*32 threads, t-major coalesced
    const int gid = (blk - 3072) * 256 + threadIdx.x;
    const int j = gid & 31;
    const int h = (gid >> 5) & 15;
    const int t = gid >> 9;
    const float a = ((float)t + delta[h]) * angles[j];
    float s, c;
    sincosf(a, &s, &c);
    tq[(size_t)t * 1024 + h * 64 + j] = f2bf((c + s) * 0.125f);
    tq[(size_t)t * 1024 + h * 64 + 32 + j] = f2bf((c - s) * 0.125f);
  } else {  // tkT: 16h*32j*256tc threads, 8 t per thread, l-major coalesced
    const int gid = (blk - 7168) * 256 + threadIdx.x;
    const int tc = gid & 255;
    const int j = (gid >> 8) & 31;
    const int h = gid >> 13;
    const float th = angles[j];
    short lo[8], hi[8];  // contiguous arrays (round-3 bug: separate short4 vars)
#pragma unroll
    for (int r = 0; r < 8; ++r) {
      float s, c;
      sincosf((float)(tc * 8 + r) * th, &s, &c);
      lo[r] = f2bf((c + s) * 0.125f);
      hi[r] = f2bf((c - s) * 0.125f);
    }
    short* base = tkT + ((size_t)h * 64 + j) * 2048 + tc * 8;
    *(short4*)(base) = *(short4*)&lo[0];
    *(short4*)(base + 4) = *(short4*)&lo[4];
    short* base2 = tkT + ((size_t)h * 64 + 32 + j) * 2048 + tc * 8;
    *(short4*)(base2) = *(short4*)&hi[0];
    *(short4*)(base2 + 4) = *(short4*)&hi[4];
  }
}

// ---------------- fused K+V GEMM + masked softmax + kv, writes kvT[b,h][d][t]
// block: 128 rows x 1 head. waves 0,1: K rows 0-63/64-127; waves 2,3: V.
__global__ __launch_bounds__(256) void kvgemm_kernel(
    const short* __restrict__ xb, const short* __restrict__ Wkb,
    const short* __restrict__ Wvb, const float* __restrict__ bk,
    const float* __restrict__ bv, const int* __restrict__ mask,
    short* __restrict__ kvT) {
  __shared__ short As[128][32];
  __shared__ short Bk[64][32];
  __shared__ short Bv[64][32];
  __shared__ short Vs[128][64];
  const int h = blockIdx.x;
  const int row0 = blockIdx.y * 128;
  const int t = threadIdx.x;
  const int lane = t & 63;
  const int wv = t >> 6;
  const bool isV = wv >= 2;
  const int wrow = (wv & 1) * 64;
  const int lrow = lane & 15;
  const int kg = (lane >> 4) * 8;
  const int srow = t >> 2;
  const int skb = (t & 3) * 8;
  const short* ga = xb + (size_t)(row0 + srow) * 1024 + skb;
  const short* gk = Wkb + (size_t)(h * 64 + srow) * 1024 + skb;
  const short* gv = Wvb + (size_t)(h * 64 + srow) * 1024 + skb;

  f32x4 acc[4][4] = {};
  for (int k0 = 0; k0 < 1024; k0 += 32) {
    GLD_LDS(ga + k0, &As[srow][skb]);
    GLD_LDS(ga + 64 * 1024 + k0, &As[64 + srow][skb]);
    GLD_LDS(gk + k0, &Bk[srow][skb]);
    GLD_LDS(gv + k0, &Bv[srow][skb]);
    __syncthreads();
    bfx8 af[4], bf_[4];
#pragma unroll
    for (int i = 0; i < 4; ++i) af[i] = *(const bfx8*)&As[wrow + i * 16 + lrow][kg];
    const short(*Bs)[32] = isV ? Bv : Bk;
#pragma unroll
    for (int j = 0; j < 4; ++j) bf_[j] = *(const bfx8*)&Bs[j * 16 + lrow][kg];
#pragma unroll
    for (int i = 0; i < 4; ++i)
#pragma unroll
      for (int j = 0; j < 4; ++j)
        acc[i][j] = __builtin_amdgcn_mfma_f32_16x16x32_bf16(af[i], bf_[j], acc[i][j], 0, 0, 0);
    __syncthreads();
  }
  // V waves: add bias, park V in LDS (bf16)
  const int rq = (lane >> 4) * 4;  // row quad base within fragment
  if (isV) {
#pragma unroll
    for (int j = 0; j < 4; ++j) {
      const float bb = bv[h * 64 + j * 16 + lrow];
#pragma unroll
      for (int i = 0; i < 4; ++i)
#pragma unroll
        for (int rr = 0; rr < 4; ++rr)
          Vs[wrow + rq + i * 16 + rr][j * 16 + lrow] = f2bf(acc[i][j][rr] + bb);
    }
  }
  __syncthreads();
  // K waves: masked softmax over head dim, multiply by V, write kvT
  if (!isV) {
    float bkc[4];
#pragma unroll
    for (int j = 0; j < 4; ++j) bkc[j] = bk[h * 64 + j * 16 + lrow];
    const int rowg0 = row0 + wrow + rq;
#pragma unroll
    for (int i = 0; i < 4; ++i) {
#pragma unroll
      for (int rr = 0; rr < 4; ++rr) {
        const float m = (float)mask[rowg0 + i * 16 + rr];
        float kf[4];
#pragma unroll
        for (int j = 0; j < 4; ++j) kf[j] = (acc[i][j][rr] + bkc[j]) * m;
        float mx = fmaxf(fmaxf(kf[0], kf[1]), fmaxf(kf[2], kf[3]));
#pragma unroll
        for (int off = 8; off >= 1; off >>= 1) mx = fmaxf(mx, __shfl_xor(mx, off));
        float s = 0.0f;
#pragma unroll
        for (int j = 0; j < 4; ++j) { kf[j] = expf(kf[j] - mx); s += kf[j]; }
#pragma unroll
        for (int off = 8; off >= 1; off >>= 1) s += __shfl_xor(s, off);
        const float inv = 1.0f / s;
#pragma unroll
        for (int j = 0; j < 4; ++j)
          acc[i][j][rr] = kf[j] * inv *
                          bf2f(Vs[wrow + rq + i * 16 + rr][j * 16 + lrow]);
      }
    }
    const int bb = row0 >> 11;
    const int tb = row0 - (bb << 11) + wrow + rq;
    short* kvb = kvT + ((size_t)(bb * 16 + h)) * 64 * 2048;
#pragma unroll
    for (int j = 0; j < 4; ++j) {
      const int d = j * 16 + lrow;
#pragma unroll
      for (int i = 0; i < 4; ++i) {
        short4 o;
        o.x = f2bf(acc[i][j][0]); o.y = f2bf(acc[i][j][1]);
        o.z = f2bf(acc[i][j][2]); o.w = f2bf(acc[i][j][3]);
        *(short4*)&kvb[(size_t)d * 2048 + tb + i * 16] = o;
      }
    }
  }
}

// ---------------- Mt_eT[b,h][e][d] += sum_l kvT[b,h][d][l] * tkT[h][e][l]
// split-K=8 (l chunks of 256), bf16 MFMA, fp32 atomics.
__global__ __launch_bounds__(256) void mt_kernel(
    const short* __restrict__ kvT, const short* __restrict__ tkT,
    float* __restrict__ Mt) {
  __shared__ short As[64][32];
  __shared__ short Bs[64][32];
  const int kc = blockIdx.x & 7;
  const int bh = blockIdx.x >> 3;
  const int h = bh & 15;
  const int l0 = kc * 256;
  const int t = threadIdx.x;
  const int lane = t & 63;
  const int w = t >> 6;
  const int lrow = lane & 15;
  const int kg = (lane >> 4) * 8;
  const int srow = t >> 2;
  const int skb = (t & 3) * 8;
  const short* ga = kvT + (size_t)bh * 131072 + (size_t)srow * 2048 + l0 + skb;
  const short* gb = tkT + (size_t)h * 131072 + (size_t)srow * 2048 + l0 + skb;
  f32x4 acc[4] = {};
  for (int k0 = 0; k0 < 256; k0 += 32) {
    GLD_LDS(ga + k0, &As[srow][skb]);
    GLD_LDS(gb + k0, &Bs[srow][skb]);
    __syncthreads();
    const bfx8 af = *(const bfx8*)&As[w * 16 + lrow][kg];
#pragma unroll
    for (int j = 0; j < 4; ++j) {
      const bfx8 bf_ = *(const bfx8*)&Bs[j * 16 + lrow][kg];
      acc[j] = __builtin_amdgcn_mfma_f32_16x16x32_bf16(af, bf_, acc[j], 0, 0, 0);
    }
    __syncthreads();
  }
  float* Mb = Mt + (size_t)bh * 4096;
#pragma unroll
  for (int j = 0; j < 4; ++j) {
    const int e = j * 16 + lrow;
#pragma unroll
    for (int rr = 0; rr < 4; ++rr) {
      const int d = w * 16 + (lane >> 4) * 4 + rr;
      atomicAdd(&Mb[(size_t)e * 64 + d], acc[j][rr]);
    }
  }
}

// ---------------- G_T[b][o][h*64+e] = sum_d Wob[o,h*64+d] * Mt_eT[b,h][e][d]
__global__ __launch_bounds__(256) void gmat_kernel(
    const short* __restrict__ Wob, const float* __restrict__ Mt,
    short* __restrict__ G_T) {
  __shared__ short Bs[64][64];
  const int o0 = blockIdx.x * 128;
  const int bh = blockIdx.y;
  const int b = bh >> 4, h = bh & 15;
  const int t = threadIdx.x;
  // stage Mt_eT (fp32) -> bf16 LDS
  {
    const int e = t >> 2;
    const int d0 = (t & 3) * 16;
    const float* src = Mt + (size_t)bh * 4096 + e * 64 + d0;
#pragma unroll
    for (int c = 0; c < 16; c += 4) {
      const float4 v = *(const float4*)(src + c);
      Bs[e][d0 + c] = f2bf(v.x); Bs[e][d0 + c + 1] = f2bf(v.y);
      Bs[e][d0 + c + 2] = f2bf(v.z); Bs[e][d0 + c + 3] = f2bf(v.w);
    }
  }
  __syncthreads();
  const int lane = t & 63;
  const int w = t >> 6;
  const int lrow = lane & 15;
  const int kg = (lane >> 4) * 8;
  const int ob = o0 + w * 32;
  f32x4 acc[2][4] = {};
#pragma unroll
  for (int k0 = 0; k0 < 64; k0 += 32) {
    bfx8 af[2], bf_[4];
#pragma unroll
    for (int i = 0; i < 2; ++i)
      af[i] = *(const bfx8*)(Wob + (size_t)(ob + i * 16 + lrow) * 1024 + h * 64 + kg + k0);
#pragma unroll
    for (int j = 0; j < 4; ++j) bf_[j] = *(const bfx8*)&Bs[j * 16 + lrow][kg + k0];
#pragma unroll
    for (int i = 0; i < 2; ++i)
#pragma unroll
      for (int j = 0; j < 4; ++j)
        acc[i][j] = __builtin_amdgcn_mfma_f32_16x16x32_bf16(af[i], bf_[j], acc[i][j], 0, 0, 0);
  }
  short* Gb = G_T + (size_t)b * 1048576 + h * 64;
#pragma unroll
  for (int i = 0; i < 2; ++i)
#pragma unroll
    for (int j = 0; j < 4; ++j)
#pragma unroll
      for (int rr = 0; rr < 4; ++rr) {
        const int o = ob + i * 16 + (lane >> 4) * 4 + rr;
        Gb[(size_t)o * 1024 + j * 16 + lrow] = f2bf(acc[i][j][rr]);
      }
}

// ---------------- out[b] = tq @ G_T[b]^T(NT) + bo, 128x64 tiles ----------------
__global__ __launch_bounds__(256) void ogemm_kernel(
    const short* __restrict__ tq, const short* __restrict__ G_T,
    const float* __restrict__ bo, float* __restrict__ out) {
  __shared__ short As[128][32];
  __shared__ short Bs[64][32];
  const int col0 = blockIdx.x * 64;
  const int row0 = blockIdx.y * 128;
  const int b = blockIdx.z;
  const short* Bm = G_T + (size_t)b * 1048576;
  float* C = out + (size_t)b * 2097152;
  const int t = threadIdx.x;
  const int lane = t & 63;
  const int wv = t >> 6;
  const int wm = (wv & 1) * 64, wn = (wv >> 1) * 32;
  const int lrow = lane & 15;
  const int kg = (lane >> 4) * 8;
  const int srow = t >> 2;
  const int skb = (t & 3) * 8;
  const short* ga = tq + (size_t)(row0 + srow) * 1024 + skb;
  const short* gb = Bm + (size_t)(col0 + srow) * 1024 + skb;
  f32x4 acc[4][2] = {};
  for (int k0 = 0; k0 < 1024; k0 += 32) {
    GLD_LDS(ga + k0, &As[srow][skb]);
    GLD_LDS(ga + 64 * 1024 + k0, &As[64 + srow][skb]);
    GLD_LDS(gb + k0, &Bs[srow][skb]);
    __syncthreads();
    bfx8 af[4], bf_[2];
#pragma unroll
    for (int i = 0; i < 4; ++i) af[i] = *(const bfx8*)&As[wm + i * 16 + lrow][kg];
#pragma unroll
    for (int j = 0; j < 2; ++j) bf_[j] = *(const bfx8*)&Bs[wn + j * 16 + lrow][kg];
#pragma unroll
    for (int i = 0; i < 4; ++i)
#pragma unroll
      for (int j = 0; j < 2; ++j)
        acc[i][j] = __builtin_amdgcn_mfma_f32_16x16x32_bf16(af[i], bf_[j], acc[i][j], 0, 0, 0);
    __syncthreads();
  }
  const int rq = (lane >> 4) * 4;
#pragma unroll
  for (int j = 0; j < 2; ++j) {
    const int c = col0 + wn + j * 16 + lrow;
    const float bb = bo[c];
#pragma unroll
    for (int i = 0; i < 4; ++i) {
      const int r = row0 + wm + i * 16 + rq;
#pragma unroll
      for (int rr = 0; rr < 4; ++rr)
        C[(size_t)(r + rr) * 1024 + c] = acc[i][j][rr] + bb;
    }
  }
}

extern "C" void kernel_launch(void* const* d_in, const int* in_sizes, int n_in,
                              void* d_out, int out_size, void* d_ws, size_t ws_size,
                              hipStream_t stream) {
  (void)in_sizes; (void)n_in; (void)out_size; (void)ws_size;
  const float* states = (const float*)d_in[0];
  const int* mask = (const int*)d_in[1];
  const float* ln_w = (const float*)d_in[2];
  const float* angles = (const float*)d_in[3];
  const float* delta = (const float*)d_in[4];
  // d_in[5]=Wq, d_in[6]=q_bias provably unused (softmax row-sums are 1).
  const float* Wk = (const float*)d_in[7];
  const float* bk = (const float*)d_in[8];
  const float* Wv = (const float*)d_in[9];
  const float* bv = (const float*)d_in[10];
  const float* Wo = (const float*)d_in[11];
  const float* bo = (const float*)d_in[12];
  float* out = (float*)d_out;

  char* W = (char*)d_ws;
  short* xb  = (short*)(W);                       // 8 MB  [4096][1024]
  short* Wkb = (short*)(W + (8u << 20));          // 2 MB
  short* Wvb = (short*)(W + (10u << 20));         // 2 MB
  short* Wob = (short*)(W + (12u << 20));         // 2 MB
  short* tq  = (short*)(W + (14u << 20));         // 4 MB  [2048][1024]
  short* tkT = (short*)(W + (18u << 20));         // 4 MB  [16][64][2048]
  short* kvT = (short*)(W + (22u << 20));         // 8 MB  [32][64][2048]
  short* G_T = (short*)(W + (30u << 20));         // 4 MB  [2][1024][1024]
  float* Mt  = (float*)(W + (34u << 20));         // 512 KB [32][64][64]

  prep_kernel<<<7680, 256, 0, stream>>>(Wk, Wv, Wo, angles, delta, Wkb, Wvb, Wob, tq, tkT);
  rmsnorm_kernel<<<4096, 256, 0, stream>>>(states, ln_w, xb);
  hipMemsetAsync(Mt, 0, 32 * 4096 * sizeof(float), stream);
  kvgemm_kernel<<<dim3(16, 32), 256, 0, stream>>>(xb, Wkb, Wvb, bk, bv, mask, kvT);
  mt_kernel<<<256, 256, 0, stream>>>(kvT, tkT, Mt);
  gmat_kernel<<<dim3(8, 32), 256, 0, stream>>>(Wob, Mt, G_T);
  ogemm_kernel<<<dim3(16, 16, 2), 256, 0, stream>>>(tq, G_T, bo, out);
}

// Round 5
// 178.207 us; speedup vs baseline: 2.9733x; 1.0421x over previous
//
#include <hip/hip_runtime.h>
#include <math.h>

#define T_ 2048
#define H_ 16

typedef __attribute__((ext_vector_type(8))) short bfx8;   // 8 bf16 = 4 VGPRs
typedef __attribute__((ext_vector_type(4))) float f32x4;  // MFMA accumulator

__device__ __forceinline__ short f2bf(float f) {
  union { float f; unsigned u; } x; x.f = f;
  unsigned r = (x.u + 0x7FFFu + ((x.u >> 16) & 1u)) >> 16;  // RNE
  return (short)r;
}
__device__ __forceinline__ float bf2f(short s) {
  union { unsigned u; float f; } x;
  x.u = ((unsigned)(unsigned short)s) << 16;
  return x.f;
}

#define GLD_LDS(g, l) \
  __builtin_amdgcn_global_load_lds( \
      (const __attribute__((address_space(1))) void*)(g), \
      (__attribute__((address_space(3))) void*)(l), 16, 0, 0)

// ---------------- prep: weight cvt + RMSNorm + Cb basis + shared tk table ----
// blk [0,3072): Wk/Wv/Wo fp32->bf16
// blk [3072,7168): RMSNorm row -> xb bf16
// blk [7168,7424): Cb[t][j]=0.125cos(t*th_j), Cb[t][32+j]=0.125sin(t*th_j)
// blk [7424,7456): tkT[j][l]=0.125(c+s), tkT[32+j][l]=0.125(c-s), c/s at l*th_j
__global__ __launch_bounds__(256) void prep_kernel(
    const float* __restrict__ Wk, const float* __restrict__ Wv,
    const float* __restrict__ Wo, const float* __restrict__ angles,
    const float* __restrict__ states, const float* __restrict__ ln_w,
    short* __restrict__ Wkb, short* __restrict__ Wvb, short* __restrict__ Wob,
    short* __restrict__ xb, short* __restrict__ Cb, short* __restrict__ tkT) {
  const int blk = blockIdx.x;
  if (blk < 3072) {
    const int i = blk * 256 + threadIdx.x;
    const int which = i >> 18;
    const int idx = i & 262143;
    const float* s = (which == 0) ? Wk : (which == 1) ? Wv : Wo;
    short* d = (which == 0) ? Wkb : (which == 1) ? Wvb : Wob;
    const float4 v = ((const float4*)s)[idx];
    short4 r;
    r.x = f2bf(v.x); r.y = f2bf(v.y); r.z = f2bf(v.z); r.w = f2bf(v.w);
    ((short4*)d)[idx] = r;
  } else if (blk < 7168) {
    const int row = blk - 3072;
    const int tid = threadIdx.x;
    const float4 v = ((const float4*)(states + (size_t)row * 1024))[tid];
    float ss = v.x * v.x + v.y * v.y + v.z * v.z + v.w * v.w;
#pragma unroll
    for (int off = 32; off >= 1; off >>= 1) ss += __shfl_xor(ss, off);
    __shared__ float red[4];
    if ((tid & 63) == 0) red[tid >> 6] = ss;
    __syncthreads();
    const float tot = red[0] + red[1] + red[2] + red[3];
    const float scale = rsqrtf(tot * (1.0f / 1024.0f) + 1.1920928955078125e-07f);
    const float4 w = ((const float4*)ln_w)[tid];
    short4 o;
    o.x = f2bf(v.x * scale * w.x);
    o.y = f2bf(v.y * scale * w.y);
    o.z = f2bf(v.z * scale * w.z);
    o.w = f2bf(v.w * scale * w.w);
    ((short4*)(xb + (size_t)row * 1024))[tid] = o;
  } else if (blk < 7424) {
    const int gid = (blk - 7168) * 256 + threadIdx.x;  // 64K: (t,j)
    const int j = gid & 31;
    const int t = gid >> 5;
    float s, c;
    sincosf((float)t * angles[j], &s, &c);
    Cb[(size_t)t * 64 + j] = f2bf(0.125f * c);
    Cb[(size_t)t * 64 + 32 + j] = f2bf(0.125f * s);
  } else {
    const int gid = (blk - 7424) * 256 + threadIdx.x;  // 8K: (j, l-chunk)
    const int tc = gid & 255;
    const int j = gid >> 8;
    const float th = angles[j];
    short lo[8], hi[8];
#pragma unroll
    for (int r = 0; r < 8; ++r) {
      float s, c;
      sincosf((float)(tc * 8 + r) * th, &s, &c);
      lo[r] = f2bf((c + s) * 0.125f);
      hi[r] = f2bf((c - s) * 0.125f);
    }
    short* base = tkT + (size_t)j * 2048 + tc * 8;
    *(short4*)(base) = *(short4*)&lo[0];
    *(short4*)(base + 4) = *(short4*)&lo[4];
    short* base2 = tkT + (size_t)(32 + j) * 2048 + tc * 8;
    *(short4*)(base2) = *(short4*)&hi[0];
    *(short4*)(base2 + 4) = *(short4*)&hi[4];
  }
}

// ---------------- fused K+V GEMM + masked softmax + kv, writes kvT[b,h][d][t]
__global__ __launch_bounds__(256) void kvgemm_kernel(
    const short* __restrict__ xb, const short* __restrict__ Wkb,
    const short* __restrict__ Wvb, const float* __restrict__ bk,
    const float* __restrict__ bv, const int* __restrict__ mask,
    short* __restrict__ kvT) {
  __shared__ short As[128][32];
  __shared__ short Bk[64][32];
  __shared__ short Bv[64][32];
  __shared__ short Vs[128][64];
  const int h = blockIdx.x;
  const int row0 = blockIdx.y * 128;
  const int t = threadIdx.x;
  const int lane = t & 63;
  const int wv = t >> 6;
  const bool isV = wv >= 2;
  const int wrow = (wv & 1) * 64;
  const int lrow = lane & 15;
  const int kg = (lane >> 4) * 8;
  const int srow = t >> 2;
  const int skb = (t & 3) * 8;
  const short* ga = xb + (size_t)(row0 + srow) * 1024 + skb;
  const short* gk = Wkb + (size_t)(h * 64 + srow) * 1024 + skb;
  const short* gv = Wvb + (size_t)(h * 64 + srow) * 1024 + skb;

  f32x4 acc[4][4] = {};
  for (int k0 = 0; k0 < 1024; k0 += 32) {
    GLD_LDS(ga + k0, &As[srow][skb]);
    GLD_LDS(ga + 64 * 1024 + k0, &As[64 + srow][skb]);
    GLD_LDS(gk + k0, &Bk[srow][skb]);
    GLD_LDS(gv + k0, &Bv[srow][skb]);
    __syncthreads();
    bfx8 af[4], bf_[4];
#pragma unroll
    for (int i = 0; i < 4; ++i) af[i] = *(const bfx8*)&As[wrow + i * 16 + lrow][kg];
    const short(*Bs)[32] = isV ? Bv : Bk;
#pragma unroll
    for (int j = 0; j < 4; ++j) bf_[j] = *(const bfx8*)&Bs[j * 16 + lrow][kg];
#pragma unroll
    for (int i = 0; i < 4; ++i)
#pragma unroll
      for (int j = 0; j < 4; ++j)
        acc[i][j] = __builtin_amdgcn_mfma_f32_16x16x32_bf16(af[i], bf_[j], acc[i][j], 0, 0, 0);
    __syncthreads();
  }
  const int rq = (lane >> 4) * 4;
  if (isV) {
#pragma unroll
    for (int j = 0; j < 4; ++j) {
      const float bb = bv[h * 64 + j * 16 + lrow];
#pragma unroll
      for (int i = 0; i < 4; ++i)
#pragma unroll
        for (int rr = 0; rr < 4; ++rr)
          Vs[wrow + rq + i * 16 + rr][j * 16 + lrow] = f2bf(acc[i][j][rr] + bb);
    }
  }
  __syncthreads();
  if (!isV) {
    float bkc[4];
#pragma unroll
    for (int j = 0; j < 4; ++j) bkc[j] = bk[h * 64 + j * 16 + lrow];
    const int rowg0 = row0 + wrow + rq;
#pragma unroll
    for (int i = 0; i < 4; ++i) {
#pragma unroll
      for (int rr = 0; rr < 4; ++rr) {
        const float m = (float)mask[rowg0 + i * 16 + rr];
        float kf[4];
#pragma unroll
        for (int j = 0; j < 4; ++j) kf[j] = (acc[i][j][rr] + bkc[j]) * m;
        float mx = fmaxf(fmaxf(kf[0], kf[1]), fmaxf(kf[2], kf[3]));
#pragma unroll
        for (int off = 8; off >= 1; off >>= 1) mx = fmaxf(mx, __shfl_xor(mx, off));
        float s = 0.0f;
#pragma unroll
        for (int j = 0; j < 4; ++j) { kf[j] = expf(kf[j] - mx); s += kf[j]; }
#pragma unroll
        for (int off = 8; off >= 1; off >>= 1) s += __shfl_xor(s, off);
        const float inv = 1.0f / s;
#pragma unroll
        for (int j = 0; j < 4; ++j)
          acc[i][j][rr] = kf[j] * inv *
                          bf2f(Vs[wrow + rq + i * 16 + rr][j * 16 + lrow]);
      }
    }
    const int bb = row0 >> 11;
    const int tb = row0 - (bb << 11) + wrow + rq;
    short* kvb = kvT + ((size_t)(bb * 16 + h)) * 64 * 2048;
#pragma unroll
    for (int j = 0; j < 4; ++j) {
      const int d = j * 16 + lrow;
#pragma unroll
      for (int i = 0; i < 4; ++i) {
        short4 o;
        o.x = f2bf(acc[i][j][0]); o.y = f2bf(acc[i][j][1]);
        o.z = f2bf(acc[i][j][2]); o.w = f2bf(acc[i][j][3]);
        *(short4*)&kvb[(size_t)d * 2048 + tb + i * 16] = o;
      }
    }
  }
}

// ---------------- Mt[b,h][e][d] += sum_l kvT[b,h][d][l] * tkT[e][l] (h-shared)
__global__ __launch_bounds__(256) void mt_kernel(
    const short* __restrict__ kvT, const short* __restrict__ tkT,
    float* __restrict__ Mt) {
  __shared__ short As[64][32];
  __shared__ short Bs[64][32];
  const int kc = blockIdx.x & 7;
  const int bh = blockIdx.x >> 3;
  const int l0 = kc * 256;
  const int t = threadIdx.x;
  const int lane = t & 63;
  const int w = t >> 6;
  const int lrow = lane & 15;
  const int kg = (lane >> 4) * 8;
  const int srow = t >> 2;
  const int skb = (t & 3) * 8;
  const short* ga = kvT + (size_t)bh * 131072 + (size_t)srow * 2048 + l0 + skb;
  const short* gb = tkT + (size_t)srow * 2048 + l0 + skb;
  f32x4 acc[4] = {};
  for (int k0 = 0; k0 < 256; k0 += 32) {
    GLD_LDS(ga + k0, &As[srow][skb]);
    GLD_LDS(gb + k0, &Bs[srow][skb]);
    __syncthreads();
    const bfx8 af = *(const bfx8*)&As[w * 16 + lrow][kg];
#pragma unroll
    for (int j = 0; j < 4; ++j) {
      const bfx8 bf_ = *(const bfx8*)&Bs[j * 16 + lrow][kg];
      acc[j] = __builtin_amdgcn_mfma_f32_16x16x32_bf16(af, bf_, acc[j], 0, 0, 0);
    }
    __syncthreads();
  }
  float* Mb = Mt + (size_t)bh * 4096;
#pragma unroll
  for (int j = 0; j < 4; ++j) {
    const int e = j * 16 + lrow;
#pragma unroll
    for (int rr = 0; rr < 4; ++rr) {
      const int d = w * 16 + (lane >> 4) * 4 + rr;
      atomicAdd(&Mb[(size_t)e * 64 + d], acc[j][rr]);
    }
  }
}

// ---------------- fold: Mf[b][j][h*64+d]    = p*Mt[b,h][j][d] + q*Mt[b,h][32+j][d]
//                        Mf[b][32+j][h*64+d] = q*Mt[b,h][j][d] - p*Mt[b,h][32+j][d]
// p=cos(phi)+sin(phi), q=cos(phi)-sin(phi), phi=delta[h]*angles[j]
__global__ __launch_bounds__(256) void fold_kernel(
    const float* __restrict__ Mt, const float* __restrict__ angles,
    const float* __restrict__ delta, short* __restrict__ Mf) {
  const int bh = blockIdx.x;
  const int b = bh >> 4, h = bh & 15;
  const int t = threadIdx.x;
  const int j = t >> 3;          // 0..31
  const int d8 = (t & 7) * 8;    // 8 d values
  float sphi, cphi;
  sincosf(delta[h] * angles[j], &sphi, &cphi);
  const float p = cphi + sphi, q = cphi - sphi;
  const float* m0 = Mt + (size_t)bh * 4096 + (size_t)j * 64 + d8;
  const float* m1 = Mt + (size_t)bh * 4096 + (size_t)(32 + j) * 64 + d8;
  short* oc = Mf + (size_t)b * 65536 + (size_t)j * 1024 + h * 64 + d8;
  short* os = Mf + (size_t)b * 65536 + (size_t)(32 + j) * 1024 + h * 64 + d8;
#pragma unroll
  for (int c = 0; c < 8; ++c) {
    const float a = m0[c], bb = m1[c];
    oc[c] = f2bf(p * a + q * bb);
    os[c] = f2bf(q * a - p * bb);
  }
}

// ---------------- H[b][o][kap] += sum_k Wob[o][k] * Mf[b][kap][k], split-K=8
__global__ __launch_bounds__(256) void hgemm_kernel(
    const short* __restrict__ Wob, const short* __restrict__ Mf,
    float* __restrict__ H) {
  const int kc = blockIdx.x;        // 0..7
  const int o0 = blockIdx.y * 64;   // 16 tiles
  const int b = blockIdx.z;
  const int t = threadIdx.x;
  const int lane = t & 63;
  const int w = t >> 6;
  const int lrow = lane & 15;
  const int kg = (lane >> 4) * 8;
  const int orow = o0 + w * 16 + lrow;
  f32x4 acc[4] = {};
#pragma unroll
  for (int it = 0; it < 4; ++it) {
    const int kb = kc * 128 + it * 32 + kg;
    const bfx8 af = *(const bfx8*)(Wob + (size_t)orow * 1024 + kb);
#pragma unroll
    for (int j = 0; j < 4; ++j) {
      const bfx8 bf_ = *(const bfx8*)(Mf + (size_t)b * 65536 +
                                      (size_t)(j * 16 + lrow) * 1024 + kb);
      acc[j] = __builtin_amdgcn_mfma_f32_16x16x32_bf16(af, bf_, acc[j], 0, 0, 0);
    }
  }
  float* Hb = H + (size_t)b * 65536;
#pragma unroll
  for (int j = 0; j < 4; ++j) {
    const int kap = j * 16 + lrow;
#pragma unroll
    for (int rr = 0; rr < 4; ++rr) {
      const int o = o0 + w * 16 + (lane >> 4) * 4 + rr;
      atomicAdd(&Hb[(size_t)o * 64 + kap], acc[j][rr]);
    }
  }
}

// ---------------- out[b][t][o] = sum_kap Cb[t][kap]*H[b][o][kap] + bo[o] ------
// K=64 skinny GEMM, 128x128 tiles, direct global fragments (Cb/H are L2-hot).
__global__ __launch_bounds__(256) void ofinal_kernel(
    const short* __restrict__ Cb, const float* __restrict__ H,
    const float* __restrict__ bo, float* __restrict__ out) {
  const int col0 = blockIdx.x * 128;
  const int row0 = blockIdx.y * 128;
  const int b = blockIdx.z;
  float* C = out + (size_t)b * 2097152;
  const float* Hb = H + (size_t)b * 65536;
  const int t = threadIdx.x;
  const int lane = t & 63;
  const int wv = t >> 6;
  const int wm = (wv & 1) * 64, wn = (wv >> 1) * 64;
  const int lrow = lane & 15;
  const int kg = (lane >> 4) * 8;
  f32x4 acc[4][4] = {};
#pragma unroll
  for (int k0 = 0; k0 < 64; k0 += 32) {
    bfx8 af[4], bf_[4];
#pragma unroll
    for (int i = 0; i < 4; ++i)
      af[i] = *(const bfx8*)(Cb + (size_t)(row0 + wm + i * 16 + lrow) * 64 + k0 + kg);
#pragma unroll
    for (int j = 0; j < 4; ++j) {
      const float* hp = Hb + (size_t)(col0 + wn + j * 16 + lrow) * 64 + k0 + kg;
      const float4 h0 = *(const float4*)hp;
      const float4 h1 = *(const float4*)(hp + 4);
      bfx8 bb;
      bb[0] = f2bf(h0.x); bb[1] = f2bf(h0.y); bb[2] = f2bf(h0.z); bb[3] = f2bf(h0.w);
      bb[4] = f2bf(h1.x); bb[5] = f2bf(h1.y); bb[6] = f2bf(h1.z); bb[7] = f2bf(h1.w);
      bf_[j] = bb;
    }
#pragma unroll
    for (int i = 0; i < 4; ++i)
#pragma unroll
      for (int j = 0; j < 4; ++j)
        acc[i][j] = __builtin_amdgcn_mfma_f32_16x16x32_bf16(af[i], bf_[j], acc[i][j], 0, 0, 0);
  }
  const int rq = (lane >> 4) * 4;
#pragma unroll
  for (int j = 0; j < 4; ++j) {
    const int c = col0 + wn + j * 16 + lrow;
    const float bb = bo[c];
#pragma unroll
    for (int i = 0; i < 4; ++i) {
      const int r = row0 + wm + i * 16 + rq;
#pragma unroll
      for (int rr = 0; rr < 4; ++rr)
        C[(size_t)(r + rr) * 1024 + c] = acc[i][j][rr] + bb;
    }
  }
}

extern "C" void kernel_launch(void* const* d_in, const int* in_sizes, int n_in,
                              void* d_out, int out_size, void* d_ws, size_t ws_size,
                              hipStream_t stream) {
  (void)in_sizes; (void)n_in; (void)out_size; (void)ws_size;
  const float* states = (const float*)d_in[0];
  const int* mask = (const int*)d_in[1];
  const float* ln_w = (const float*)d_in[2];
  const float* angles = (const float*)d_in[3];
  const float* delta = (const float*)d_in[4];
  // d_in[5]=Wq, d_in[6]=q_bias provably unused (softmax row-sums are 1).
  const float* Wk = (const float*)d_in[7];
  const float* bk = (const float*)d_in[8];
  const float* Wv = (const float*)d_in[9];
  const float* bv = (const float*)d_in[10];
  const float* Wo = (const float*)d_in[11];
  const float* bo = (const float*)d_in[12];
  float* out = (float*)d_out;

  char* W = (char*)d_ws;
  short* xb  = (short*)(W);                        // 8 MB   [4096][1024]
  short* Wkb = (short*)(W + (8u << 20));           // 2 MB
  short* Wvb = (short*)(W + (10u << 20));          // 2 MB
  short* Wob = (short*)(W + (12u << 20));          // 2 MB
  short* kvT = (short*)(W + (14u << 20));          // 8 MB   [32][64][2048]
  short* Cb  = (short*)(W + (22u << 20));          // 256 KB [2048][64]
  short* tkT = (short*)(W + (22u << 20) + (256u << 10));  // 256 KB [64][2048]
  short* Mf  = (short*)(W + (22u << 20) + (512u << 10));  // 256 KB [2][64][1024]
  float* Mt  = (float*)(W + (23u << 20));          // 512 KB [32][64][64]
  float* H   = (float*)(W + (23u << 20) + (512u << 10));  // 512 KB [2][1024][64]

  hipMemsetAsync(Mt, 0, (1u << 20), stream);  // zeros Mt + H (contiguous)
  prep_kernel<<<7456, 256, 0, stream>>>(Wk, Wv, Wo, angles, states, ln_w,
                                        Wkb, Wvb, Wob, xb, Cb, tkT);
  kvgemm_kernel<<<dim3(16, 32), 256, 0, stream>>>(xb, Wkb, Wvb, bk, bv, mask, kvT);
  mt_kernel<<<256, 256, 0, stream>>>(kvT, tkT, Mt);
  fold_kernel<<<32, 256, 0, stream>>>(Mt, angles, delta, Mf);
  hgemm_kernel<<<dim3(8, 16, 2), 256, 0, stream>>>(Wob, Mf, H);
  ofinal_kernel<<<dim3(8, 16, 2), 256, 0, stream>>>(Cb, H, bo, out);
}

// Round 6
// 153.269 us; speedup vs baseline: 3.4571x; 1.1627x over previous
//
#include <hip/hip_runtime.h>
#include <math.h>

#define T_ 2048
#define H_ 16

typedef __attribute__((ext_vector_type(8))) short bfx8;   // 8 bf16 = 4 VGPRs
typedef __attribute__((ext_vector_type(4))) float f32x4;  // MFMA accumulator

__device__ __forceinline__ short f2bf(float f) {
  union { float f; unsigned u; } x; x.f = f;
  unsigned r = (x.u + 0x7FFFu + ((x.u >> 16) & 1u)) >> 16;  // RNE
  return (short)r;
}
__device__ __forceinline__ float bf2f(short s) {
  union { unsigned u; float f; } x;
  x.u = ((unsigned)(unsigned short)s) << 16;
  return x.f;
}

#define GLD_LDS(g, l) \
  __builtin_amdgcn_global_load_lds( \
      (const __attribute__((address_space(1))) void*)(g), \
      (__attribute__((address_space(3))) void*)(l), 16, 0, 0)

// ---------------- prep: weight cvt + RMSNorm + Cb basis + shared tk table ----
__global__ __launch_bounds__(256) void prep_kernel(
    const float* __restrict__ Wk, const float* __restrict__ Wv,
    const float* __restrict__ Wo, const float* __restrict__ angles,
    const float* __restrict__ states, const float* __restrict__ ln_w,
    short* __restrict__ Wkb, short* __restrict__ Wvb, short* __restrict__ Wob,
    short* __restrict__ xb, short* __restrict__ Cb, short* __restrict__ tkT) {
  const int blk = blockIdx.x;
  if (blk < 3072) {
    const int i = blk * 256 + threadIdx.x;
    const int which = i >> 18;
    const int idx = i & 262143;
    const float* s = (which == 0) ? Wk : (which == 1) ? Wv : Wo;
    short* d = (which == 0) ? Wkb : (which == 1) ? Wvb : Wob;
    const float4 v = ((const float4*)s)[idx];
    short4 r;
    r.x = f2bf(v.x); r.y = f2bf(v.y); r.z = f2bf(v.z); r.w = f2bf(v.w);
    ((short4*)d)[idx] = r;
  } else if (blk < 7168) {
    const int row = blk - 3072;
    const int tid = threadIdx.x;
    const float4 v = ((const float4*)(states + (size_t)row * 1024))[tid];
    float ss = v.x * v.x + v.y * v.y + v.z * v.z + v.w * v.w;
#pragma unroll
    for (int off = 32; off >= 1; off >>= 1) ss += __shfl_xor(ss, off);
    __shared__ float red[4];
    if ((tid & 63) == 0) red[tid >> 6] = ss;
    __syncthreads();
    const float tot = red[0] + red[1] + red[2] + red[3];
    const float scale = rsqrtf(tot * (1.0f / 1024.0f) + 1.1920928955078125e-07f);
    const float4 w = ((const float4*)ln_w)[tid];
    short4 o;
    o.x = f2bf(v.x * scale * w.x);
    o.y = f2bf(v.y * scale * w.y);
    o.z = f2bf(v.z * scale * w.z);
    o.w = f2bf(v.w * scale * w.w);
    ((short4*)(xb + (size_t)row * 1024))[tid] = o;
  } else if (blk < 7424) {
    const int gid = (blk - 7168) * 256 + threadIdx.x;  // 64K: (t,j)
    const int j = gid & 31;
    const int t = gid >> 5;
    float s, c;
    sincosf((float)t * angles[j], &s, &c);
    Cb[(size_t)t * 64 + j] = f2bf(0.125f * c);
    Cb[(size_t)t * 64 + 32 + j] = f2bf(0.125f * s);
  } else {
    const int gid = (blk - 7424) * 256 + threadIdx.x;  // 8K: (j, l-chunk)
    const int tc = gid & 255;
    const int j = gid >> 8;
    const float th = angles[j];
    short lo[8], hi[8];
#pragma unroll
    for (int r = 0; r < 8; ++r) {
      float s, c;
      sincosf((float)(tc * 8 + r) * th, &s, &c);
      lo[r] = f2bf((c + s) * 0.125f);
      hi[r] = f2bf((c - s) * 0.125f);
    }
    short* base = tkT + (size_t)j * 2048 + tc * 8;
    *(short4*)(base) = *(short4*)&lo[0];
    *(short4*)(base + 4) = *(short4*)&lo[4];
    short* base2 = tkT + (size_t)(32 + j) * 2048 + tc * 8;
    *(short4*)(base2) = *(short4*)&hi[0];
    *(short4*)(base2 + 4) = *(short4*)&hi[4];
  }
}

// ------- fused K+V GEMM + masked softmax + kv + Mt accumulation -------------
// grid: x = row-chunk (32)  [XCD swizzle: XCD = x%8 -> each XCD reads 4 xb
// chunks + all weights ~5 MB instead of full xb 8.5 MB], y = head (16).
// Epilogue: kv tile (128 l x 64 d) -> LDS (overlaying dead As/Bk/Bv), then all
// 4 waves contract Mt[e][d] += sum_l tkT[e][l]*kv[l][d], atomics into Mt[b,h].
__global__ __launch_bounds__(256) void kvgemm_kernel(
    const short* __restrict__ xb, const short* __restrict__ Wkb,
    const short* __restrict__ Wvb, const float* __restrict__ bk,
    const float* __restrict__ bv, const int* __restrict__ mask,
    const short* __restrict__ tkT, float* __restrict__ Mt) {
  __shared__ short smem[8192];   // As[128][32] | Bk[64][32] | Bv[64][32] (16KB)
  __shared__ short Vs[128][64];  // 16 KB
  short(*As)[32] = (short(*)[32])smem;
  short(*Bk)[32] = (short(*)[32])(smem + 4096);
  short(*Bv)[32] = (short(*)[32])(smem + 6144);
  short(*kvS)[128] = (short(*)[128])smem;  // overlays As/Bk/Bv post-K-loop

  const int row0 = blockIdx.x * 128;
  const int h = blockIdx.y;
  const int t = threadIdx.x;
  const int lane = t & 63;
  const int wv = t >> 6;
  const bool isV = wv >= 2;
  const int wrow = (wv & 1) * 64;
  const int lrow = lane & 15;
  const int kg = (lane >> 4) * 8;
  const int srow = t >> 2;
  const int skb = (t & 3) * 8;
  const short* ga = xb + (size_t)(row0 + srow) * 1024 + skb;
  const short* gk = Wkb + (size_t)(h * 64 + srow) * 1024 + skb;
  const short* gv = Wvb + (size_t)(h * 64 + srow) * 1024 + skb;

  f32x4 acc[4][4] = {};
  for (int k0 = 0; k0 < 1024; k0 += 32) {
    GLD_LDS(ga + k0, &As[srow][skb]);
    GLD_LDS(ga + 64 * 1024 + k0, &As[64 + srow][skb]);
    GLD_LDS(gk + k0, &Bk[srow][skb]);
    GLD_LDS(gv + k0, &Bv[srow][skb]);
    __syncthreads();
    bfx8 af[4], bf_[4];
#pragma unroll
    for (int i = 0; i < 4; ++i) af[i] = *(const bfx8*)&As[wrow + i * 16 + lrow][kg];
    const short(*Bs)[32] = isV ? Bv : Bk;
#pragma unroll
    for (int j = 0; j < 4; ++j) bf_[j] = *(const bfx8*)&Bs[j * 16 + lrow][kg];
#pragma unroll
    for (int i = 0; i < 4; ++i)
#pragma unroll
      for (int j = 0; j < 4; ++j)
        acc[i][j] = __builtin_amdgcn_mfma_f32_16x16x32_bf16(af[i], bf_[j], acc[i][j], 0, 0, 0);
    __syncthreads();
  }
  const int rq = (lane >> 4) * 4;
  if (isV) {  // park V+bias in Vs
#pragma unroll
    for (int j = 0; j < 4; ++j) {
      const float bb = bv[h * 64 + j * 16 + lrow];
#pragma unroll
      for (int i = 0; i < 4; ++i)
#pragma unroll
        for (int rr = 0; rr < 4; ++rr)
          Vs[wrow + rq + i * 16 + rr][j * 16 + lrow] = f2bf(acc[i][j][rr] + bb);
    }
  }
  __syncthreads();
  if (!isV) {  // masked softmax over head dim, kv = softmax * V -> kvS[d][l]
    float bkc[4];
#pragma unroll
    for (int j = 0; j < 4; ++j) bkc[j] = bk[h * 64 + j * 16 + lrow];
    const int rowg0 = row0 + wrow + rq;
#pragma unroll
    for (int i = 0; i < 4; ++i) {
#pragma unroll
      for (int rr = 0; rr < 4; ++rr) {
        const float m = (float)mask[rowg0 + i * 16 + rr];
        float kf[4];
#pragma unroll
        for (int j = 0; j < 4; ++j) kf[j] = (acc[i][j][rr] + bkc[j]) * m;
        float mx = fmaxf(fmaxf(kf[0], kf[1]), fmaxf(kf[2], kf[3]));
#pragma unroll
        for (int off = 8; off >= 1; off >>= 1) mx = fmaxf(mx, __shfl_xor(mx, off));
        float s = 0.0f;
#pragma unroll
        for (int j = 0; j < 4; ++j) { kf[j] = expf(kf[j] - mx); s += kf[j]; }
#pragma unroll
        for (int off = 8; off >= 1; off >>= 1) s += __shfl_xor(s, off);
        const float inv = 1.0f / s;
#pragma unroll
        for (int j = 0; j < 4; ++j)
          acc[i][j][rr] = kf[j] * inv *
                          bf2f(Vs[wrow + rq + i * 16 + rr][j * 16 + lrow]);
      }
    }
#pragma unroll
    for (int j = 0; j < 4; ++j) {
      const int d = j * 16 + lrow;
#pragma unroll
      for (int i = 0; i < 4; ++i) {
        short4 o;
        o.x = f2bf(acc[i][j][0]); o.y = f2bf(acc[i][j][1]);
        o.z = f2bf(acc[i][j][2]); o.w = f2bf(acc[i][j][3]);
        *(short4*)&kvS[d][wrow + rq + i * 16] = o;
      }
    }
  }
  __syncthreads();
  // Mt contraction: wave w covers e in [w*16, w*16+16), K = 128 local l.
  const int bb = row0 >> 11;
  const int tb = row0 & 2047;
  const short* tkb = tkT + (size_t)(wv * 16 + lrow) * 2048 + tb;
  f32x4 macc[4] = {};
#pragma unroll
  for (int kc = 0; kc < 4; ++kc) {
    const bfx8 af = *(const bfx8*)(tkb + kc * 32 + kg);
#pragma unroll
    for (int j = 0; j < 4; ++j) {
      const bfx8 bf_ = *(const bfx8*)&kvS[j * 16 + lrow][kc * 32 + kg];
      macc[j] = __builtin_amdgcn_mfma_f32_16x16x32_bf16(af, bf_, macc[j], 0, 0, 0);
    }
  }
  float* Mb = Mt + (size_t)(bb * 16 + h) * 4096;
#pragma unroll
  for (int j = 0; j < 4; ++j) {
    const int d = j * 16 + lrow;
#pragma unroll
    for (int rr = 0; rr < 4; ++rr) {
      const int e = wv * 16 + rq + rr;
      atomicAdd(&Mb[(size_t)e * 64 + d], macc[j][rr]);
    }
  }
}

// ---------------- fold: Mf[b][j][h*64+d]    = p*Mt[b,h][j][d] + q*Mt[b,h][32+j][d]
//                        Mf[b][32+j][h*64+d] = q*Mt[b,h][j][d] - p*Mt[b,h][32+j][d]
__global__ __launch_bounds__(256) void fold_kernel(
    const float* __restrict__ Mt, const float* __restrict__ angles,
    const float* __restrict__ delta, short* __restrict__ Mf) {
  const int bh = blockIdx.x;
  const int b = bh >> 4, h = bh & 15;
  const int t = threadIdx.x;
  const int j = t >> 3;
  const int d8 = (t & 7) * 8;
  float sphi, cphi;
  sincosf(delta[h] * angles[j], &sphi, &cphi);
  const float p = cphi + sphi, q = cphi - sphi;
  const float* m0 = Mt + (size_t)bh * 4096 + (size_t)j * 64 + d8;
  const float* m1 = Mt + (size_t)bh * 4096 + (size_t)(32 + j) * 64 + d8;
  short* oc = Mf + (size_t)b * 65536 + (size_t)j * 1024 + h * 64 + d8;
  short* os = Mf + (size_t)b * 65536 + (size_t)(32 + j) * 1024 + h * 64 + d8;
#pragma unroll
  for (int c = 0; c < 8; ++c) {
    const float a = m0[c], bb = m1[c];
    oc[c] = f2bf(p * a + q * bb);
    os[c] = f2bf(q * a - p * bb);
  }
}

// ---------------- H[b][o][kap] += sum_k Wob[o][k] * Mf[b][kap][k], split-K=8
__global__ __launch_bounds__(256) void hgemm_kernel(
    const short* __restrict__ Wob, const short* __restrict__ Mf,
    float* __restrict__ H) {
  const int kc = blockIdx.x;
  const int o0 = blockIdx.y * 64;
  const int b = blockIdx.z;
  const int t = threadIdx.x;
  const int lane = t & 63;
  const int w = t >> 6;
  const int lrow = lane & 15;
  const int kg = (lane >> 4) * 8;
  const int orow = o0 + w * 16 + lrow;
  f32x4 acc[4] = {};
#pragma unroll
  for (int it = 0; it < 4; ++it) {
    const int kb = kc * 128 + it * 32 + kg;
    const bfx8 af = *(const bfx8*)(Wob + (size_t)orow * 1024 + kb);
#pragma unroll
    for (int j = 0; j < 4; ++j) {
      const bfx8 bf_ = *(const bfx8*)(Mf + (size_t)b * 65536 +
                                      (size_t)(j * 16 + lrow) * 1024 + kb);
      acc[j] = __builtin_amdgcn_mfma_f32_16x16x32_bf16(af, bf_, acc[j], 0, 0, 0);
    }
  }
  float* Hb = H + (size_t)b * 65536;
#pragma unroll
  for (int j = 0; j < 4; ++j) {
    const int kap = j * 16 + lrow;
#pragma unroll
    for (int rr = 0; rr < 4; ++rr) {
      const int o = o0 + w * 16 + (lane >> 4) * 4 + rr;
      atomicAdd(&Hb[(size_t)o * 64 + kap], acc[j][rr]);
    }
  }
}

// ---------------- out[b][t][o] = sum_kap Cb[t][kap]*H[b][o][kap] + bo[o] ------
__global__ __launch_bounds__(256) void ofinal_kernel(
    const short* __restrict__ Cb, const float* __restrict__ H,
    const float* __restrict__ bo, float* __restrict__ out) {
  const int col0 = blockIdx.x * 128;
  const int row0 = blockIdx.y * 128;
  const int b = blockIdx.z;
  float* C = out + (size_t)b * 2097152;
  const float* Hb = H + (size_t)b * 65536;
  const int t = threadIdx.x;
  const int lane = t & 63;
  const int wv = t >> 6;
  const int wm = (wv & 1) * 64, wn = (wv >> 1) * 64;
  const int lrow = lane & 15;
  const int kg = (lane >> 4) * 8;
  f32x4 acc[4][4] = {};
#pragma unroll
  for (int k0 = 0; k0 < 64; k0 += 32) {
    bfx8 af[4], bf_[4];
#pragma unroll
    for (int i = 0; i < 4; ++i)
      af[i] = *(const bfx8*)(Cb + (size_t)(row0 + wm + i * 16 + lrow) * 64 + k0 + kg);
#pragma unroll
    for (int j = 0; j < 4; ++j) {
      const float* hp = Hb + (size_t)(col0 + wn + j * 16 + lrow) * 64 + k0 + kg;
      const float4 h0 = *(const float4*)hp;
      const float4 h1 = *(const float4*)(hp + 4);
      bfx8 bb;
      bb[0] = f2bf(h0.x); bb[1] = f2bf(h0.y); bb[2] = f2bf(h0.z); bb[3] = f2bf(h0.w);
      bb[4] = f2bf(h1.x); bb[5] = f2bf(h1.y); bb[6] = f2bf(h1.z); bb[7] = f2bf(h1.w);
      bf_[j] = bb;
    }
#pragma unroll
    for (int i = 0; i < 4; ++i)
#pragma unroll
      for (int j = 0; j < 4; ++j)
        acc[i][j] = __builtin_amdgcn_mfma_f32_16x16x32_bf16(af[i], bf_[j], acc[i][j], 0, 0, 0);
  }
  const int rq = (lane >> 4) * 4;
#pragma unroll
  for (int j = 0; j < 4; ++j) {
    const int c = col0 + wn + j * 16 + lrow;
    const float bb = bo[c];
#pragma unroll
    for (int i = 0; i < 4; ++i) {
      const int r = row0 + wm + i * 16 + rq;
#pragma unroll
      for (int rr = 0; rr < 4; ++rr)
        C[(size_t)(r + rr) * 1024 + c] = acc[i][j][rr] + bb;
    }
  }
}

extern "C" void kernel_launch(void* const* d_in, const int* in_sizes, int n_in,
                              void* d_out, int out_size, void* d_ws, size_t ws_size,
                              hipStream_t stream) {
  (void)in_sizes; (void)n_in; (void)out_size; (void)ws_size;
  const float* states = (const float*)d_in[0];
  const int* mask = (const int*)d_in[1];
  const float* ln_w = (const float*)d_in[2];
  const float* angles = (const float*)d_in[3];
  const float* delta = (const float*)d_in[4];
  // d_in[5]=Wq, d_in[6]=q_bias provably unused (softmax row-sums are 1).
  const float* Wk = (const float*)d_in[7];
  const float* bk = (const float*)d_in[8];
  const float* Wv = (const float*)d_in[9];
  const float* bv = (const float*)d_in[10];
  const float* Wo = (const float*)d_in[11];
  const float* bo = (const float*)d_in[12];
  float* out = (float*)d_out;

  char* W = (char*)d_ws;
  short* xb  = (short*)(W);                        // 8 MB   [4096][1024]
  short* Wkb = (short*)(W + (8u << 20));           // 2 MB
  short* Wvb = (short*)(W + (10u << 20));          // 2 MB
  short* Wob = (short*)(W + (12u << 20));          // 2 MB
  short* Cb  = (short*)(W + (14u << 20));          // 256 KB [2048][64]
  short* tkT = (short*)(W + (14u << 20) + (256u << 10));  // 256 KB [64][2048]
  short* Mf  = (short*)(W + (14u << 20) + (512u << 10));  // 256 KB [2][64][1024]
  float* Mt  = (float*)(W + (15u << 20));          // 512 KB [32][64][64]
  float* H   = (float*)(W + (15u << 20) + (512u << 10));  // 512 KB [2][1024][64]

  hipMemsetAsync(Mt, 0, (1u << 20), stream);  // zeros Mt + H (contiguous)
  prep_kernel<<<7456, 256, 0, stream>>>(Wk, Wv, Wo, angles, states, ln_w,
                                        Wkb, Wvb, Wob, xb, Cb, tkT);
  kvgemm_kernel<<<dim3(32, 16), 256, 0, stream>>>(xb, Wkb, Wvb, bk, bv, mask,
                                                  tkT, Mt);
  fold_kernel<<<32, 256, 0, stream>>>(Mt, angles, delta, Mf);
  hgemm_kernel<<<dim3(8, 16, 2), 256, 0, stream>>>(Wob, Mf, H);
  ofinal_kernel<<<dim3(8, 16, 2), 256, 0, stream>>>(Cb, H, bo, out);
}

// Round 7
// 144.959 us; speedup vs baseline: 3.6553x; 1.0573x over previous
//
#include <hip/hip_runtime.h>
#include <math.h>

#define T_ 2048
#define H_ 16

typedef __attribute__((ext_vector_type(8))) short bfx8;   // 8 bf16 = 4 VGPRs
typedef __attribute__((ext_vector_type(4))) float f32x4;  // MFMA accumulator

__device__ __forceinline__ short f2bf(float f) {
  union { float f; unsigned u; } x; x.f = f;
  unsigned r = (x.u + 0x7FFFu + ((x.u >> 16) & 1u)) >> 16;  // RNE
  return (short)r;
}
__device__ __forceinline__ float bf2f(short s) {
  union { unsigned u; float f; } x;
  x.u = ((unsigned)(unsigned short)s) << 16;
  return x.f;
}

#define GLD_LDS(g, l) \
  __builtin_amdgcn_global_load_lds( \
      (const __attribute__((address_space(1))) void*)(g), \
      (__attribute__((address_space(3))) void*)(l), 16, 0, 0)

// ---------------- prep: weight cvt + RMSNorm + Cb basis + tk table + Mt/H zero
__global__ __launch_bounds__(256) void prep_kernel(
    const float* __restrict__ Wk, const float* __restrict__ Wv,
    const float* __restrict__ Wo, const float* __restrict__ angles,
    const float* __restrict__ states, const float* __restrict__ ln_w,
    short* __restrict__ Wkb, short* __restrict__ Wvb, short* __restrict__ Wob,
    short* __restrict__ xb, short* __restrict__ Cb, short* __restrict__ tkT,
    float* __restrict__ MtH) {
  const int blk = blockIdx.x;
  if (blk < 3072) {
    const int i = blk * 256 + threadIdx.x;
    const int which = i >> 18;
    const int idx = i & 262143;
    const float* s = (which == 0) ? Wk : (which == 1) ? Wv : Wo;
    short* d = (which == 0) ? Wkb : (which == 1) ? Wvb : Wob;
    const float4 v = ((const float4*)s)[idx];
    short4 r;
    r.x = f2bf(v.x); r.y = f2bf(v.y); r.z = f2bf(v.z); r.w = f2bf(v.w);
    ((short4*)d)[idx] = r;
  } else if (blk < 7168) {
    const int row = blk - 3072;
    const int tid = threadIdx.x;
    const float4 v = ((const float4*)(states + (size_t)row * 1024))[tid];
    float ss = v.x * v.x + v.y * v.y + v.z * v.z + v.w * v.w;
#pragma unroll
    for (int off = 32; off >= 1; off >>= 1) ss += __shfl_xor(ss, off);
    __shared__ float red[4];
    if ((tid & 63) == 0) red[tid >> 6] = ss;
    __syncthreads();
    const float tot = red[0] + red[1] + red[2] + red[3];
    const float scale = rsqrtf(tot * (1.0f / 1024.0f) + 1.1920928955078125e-07f);
    const float4 w = ((const float4*)ln_w)[tid];
    short4 o;
    o.x = f2bf(v.x * scale * w.x);
    o.y = f2bf(v.y * scale * w.y);
    o.z = f2bf(v.z * scale * w.z);
    o.w = f2bf(v.w * scale * w.w);
    ((short4*)(xb + (size_t)row * 1024))[tid] = o;
  } else if (blk < 7424) {
    const int gid = (blk - 7168) * 256 + threadIdx.x;  // 64K: (t,j)
    const int j = gid & 31;
    const int t = gid >> 5;
    float s, c;
    sincosf((float)t * angles[j], &s, &c);
    Cb[(size_t)t * 64 + j] = f2bf(0.125f * c);
    Cb[(size_t)t * 64 + 32 + j] = f2bf(0.125f * s);
  } else if (blk < 7456) {
    const int gid = (blk - 7424) * 256 + threadIdx.x;  // 8K: (j, l-chunk)
    const int tc = gid & 255;
    const int j = gid >> 8;
    const float th = angles[j];
    short lo[8], hi[8];
#pragma unroll
    for (int r = 0; r < 8; ++r) {
      float s, c;
      sincosf((float)(tc * 8 + r) * th, &s, &c);
      lo[r] = f2bf((c + s) * 0.125f);
      hi[r] = f2bf((c - s) * 0.125f);
    }
    short* base = tkT + (size_t)j * 2048 + tc * 8;
    *(short4*)(base) = *(short4*)&lo[0];
    *(short4*)(base + 4) = *(short4*)&lo[4];
    short* base2 = tkT + (size_t)(32 + j) * 2048 + tc * 8;
    *(short4*)(base2) = *(short4*)&hi[0];
    *(short4*)(base2 + 4) = *(short4*)&hi[4];
  } else {  // zero Mt (512 KB) + H (512 KB): 65536 float4s
    const int gid = (blk - 7456) * 256 + threadIdx.x;
    ((float4*)MtH)[gid] = make_float4(0.f, 0.f, 0.f, 0.f);
  }
}

// ------- fused K+V GEMM + masked softmax + kv + Mt accumulation -------------
// BK=64 (128 B LDS rows) + XOR-8 k-slot swizzle: element (row, kslot) lives at
// LDS slot kslot^(row&7). DMA-compatible (we swizzle the global SOURCE per
// lane; LDS dest stays base+lane*16). Fragment reads touch all 32 banks.
__global__ __launch_bounds__(256) void kvgemm_kernel(
    const short* __restrict__ xb, const short* __restrict__ Wkb,
    const short* __restrict__ Wvb, const float* __restrict__ bk,
    const float* __restrict__ bv, const int* __restrict__ mask,
    const short* __restrict__ tkT, float* __restrict__ Mt) {
  __shared__ short smem[16384];  // As[128][64] | Bk[64][64] | Bv[64][64] 32KB
  __shared__ short Vs[128][64];  // 16 KB
  short(*As)[64] = (short(*)[64])smem;
  short(*Bk)[64] = (short(*)[64])(smem + 8192);
  short(*Bv)[64] = (short(*)[64])(smem + 12288);
  short(*kvS)[132] = (short(*)[132])smem;  // padded overlay post-K-loop

  const int row0 = blockIdx.x * 128;  // XCD = x%8: 4 xb chunks + weights/XCD
  const int h = blockIdx.y;
  const int t = threadIdx.x;
  const int lane = t & 63;
  const int wv = t >> 6;
  const bool isV = wv >= 2;
  const int wrow = (wv & 1) * 64;
  const int lrow = lane & 15;

  // staging: thread t owns physical slot t&7 of row (t>>3)+32u; fetches
  // k-slot (t&7)^(row&7); row&7 == (t>>3)&7 for all issues (u*32 ≡ 0 mod 8).
  const int srow8 = t >> 3;
  const int kslotS = (t & 7) ^ (srow8 & 7);
  const short* gaS = xb + (size_t)(row0 + srow8) * 1024 + kslotS * 8;
  const short* gkS = Wkb + (size_t)(h * 64 + srow8) * 1024 + kslotS * 8;
  const short* gvS = Wvb + (size_t)(h * 64 + srow8) * 1024 + kslotS * 8;
  short* laS = &As[srow8][(t & 7) * 8];
  short* lkS = &Bk[srow8][(t & 7) * 8];
  short* lvS = &Bv[srow8][(t & 7) * 8];

  f32x4 acc[4][4] = {};
  for (int k0 = 0; k0 < 1024; k0 += 64) {
    GLD_LDS(gaS + k0, laS);
    GLD_LDS(gaS + 32 * 1024 + k0, laS + 2048);
    GLD_LDS(gaS + 64 * 1024 + k0, laS + 4096);
    GLD_LDS(gaS + 96 * 1024 + k0, laS + 6144);
    GLD_LDS(gkS + k0, lkS);
    GLD_LDS(gkS + 32 * 1024 + k0, lkS + 2048);
    GLD_LDS(gvS + k0, lvS);
    GLD_LDS(gvS + 32 * 1024 + k0, lvS + 2048);
    __syncthreads();
#pragma unroll
    for (int kk = 0; kk < 2; ++kk) {
      const int pcol = ((kk * 4 + (lane >> 4)) ^ (lrow & 7)) * 8;
      bfx8 af[4], bf_[4];
#pragma unroll
      for (int i = 0; i < 4; ++i)
        af[i] = *(const bfx8*)&As[wrow + i * 16 + lrow][pcol];
      const short(*Bs)[64] = isV ? Bv : Bk;
#pragma unroll
      for (int j = 0; j < 4; ++j)
        bf_[j] = *(const bfx8*)&Bs[j * 16 + lrow][pcol];
#pragma unroll
      for (int i = 0; i < 4; ++i)
#pragma unroll
        for (int j = 0; j < 4; ++j)
          acc[i][j] = __builtin_amdgcn_mfma_f32_16x16x32_bf16(af[i], bf_[j], acc[i][j], 0, 0, 0);
    }
    __syncthreads();
  }
  const int rq = (lane >> 4) * 4;
  if (isV) {  // park V+bias in Vs
#pragma unroll
    for (int j = 0; j < 4; ++j) {
      const float bb = bv[h * 64 + j * 16 + lrow];
#pragma unroll
      for (int i = 0; i < 4; ++i)
#pragma unroll
        for (int rr = 0; rr < 4; ++rr)
          Vs[wrow + rq + i * 16 + rr][j * 16 + lrow] = f2bf(acc[i][j][rr] + bb);
    }
  }
  __syncthreads();
  if (!isV) {  // masked softmax over head dim, kv = softmax * V -> kvS[d][l]
    float bkc[4];
#pragma unroll
    for (int j = 0; j < 4; ++j) bkc[j] = bk[h * 64 + j * 16 + lrow];
    const int rowg0 = row0 + wrow + rq;
#pragma unroll
    for (int i = 0; i < 4; ++i) {
#pragma unroll
      for (int rr = 0; rr < 4; ++rr) {
        const float m = (float)mask[rowg0 + i * 16 + rr];
        float kf[4];
#pragma unroll
        for (int j = 0; j < 4; ++j) kf[j] = (acc[i][j][rr] + bkc[j]) * m;
        float mx = fmaxf(fmaxf(kf[0], kf[1]), fmaxf(kf[2], kf[3]));
#pragma unroll
        for (int off = 8; off >= 1; off >>= 1) mx = fmaxf(mx, __shfl_xor(mx, off));
        float s = 0.0f;
#pragma unroll
        for (int j = 0; j < 4; ++j) { kf[j] = expf(kf[j] - mx); s += kf[j]; }
#pragma unroll
        for (int off = 8; off >= 1; off >>= 1) s += __shfl_xor(s, off);
        const float inv = 1.0f / s;
#pragma unroll
        for (int j = 0; j < 4; ++j)
          acc[i][j][rr] = kf[j] * inv *
                          bf2f(Vs[wrow + rq + i * 16 + rr][j * 16 + lrow]);
      }
    }
#pragma unroll
    for (int j = 0; j < 4; ++j) {
      const int d = j * 16 + lrow;
#pragma unroll
      for (int i = 0; i < 4; ++i) {
        short4 o;
        o.x = f2bf(acc[i][j][0]); o.y = f2bf(acc[i][j][1]);
        o.z = f2bf(acc[i][j][2]); o.w = f2bf(acc[i][j][3]);
        *(short4*)&kvS[d][wrow + rq + i * 16] = o;
      }
    }
  }
  __syncthreads();
  // Mt contraction: wave w covers e in [w*16, w*16+16), K = 128 local l.
  const int bb = row0 >> 11;
  const int tb = row0 & 2047;
  const short* tkb = tkT + (size_t)(wv * 16 + lrow) * 2048 + tb;
  const int kg = (lane >> 4) * 8;
  f32x4 macc[4] = {};
#pragma unroll
  for (int kc = 0; kc < 4; ++kc) {
    const bfx8 af = *(const bfx8*)(tkb + kc * 32 + kg);
#pragma unroll
    for (int j = 0; j < 4; ++j) {
      const bfx8 bf_ = *(const bfx8*)&kvS[j * 16 + lrow][kc * 32 + kg];
      macc[j] = __builtin_amdgcn_mfma_f32_16x16x32_bf16(af, bf_, macc[j], 0, 0, 0);
    }
  }
  float* Mb = Mt + (size_t)(bb * 16 + h) * 4096;
#pragma unroll
  for (int j = 0; j < 4; ++j) {
    const int d = j * 16 + lrow;
#pragma unroll
    for (int rr = 0; rr < 4; ++rr) {
      const int e = wv * 16 + rq + rr;
      atomicAdd(&Mb[(size_t)e * 64 + d], macc[j][rr]);
    }
  }
}

// ---------------- fold: Mf[b][j][h*64+d]    = p*Mt[b,h][j][d] + q*Mt[b,h][32+j][d]
//                        Mf[b][32+j][h*64+d] = q*Mt[b,h][j][d] - p*Mt[b,h][32+j][d]
__global__ __launch_bounds__(256) void fold_kernel(
    const float* __restrict__ Mt, const float* __restrict__ angles,
    const float* __restrict__ delta, short* __restrict__ Mf) {
  const int bh = blockIdx.x;
  const int b = bh >> 4, h = bh & 15;
  const int t = threadIdx.x;
  const int j = t >> 3;
  const int d8 = (t & 7) * 8;
  float sphi, cphi;
  sincosf(delta[h] * angles[j], &sphi, &cphi);
  const float p = cphi + sphi, q = cphi - sphi;
  const float* m0 = Mt + (size_t)bh * 4096 + (size_t)j * 64 + d8;
  const float* m1 = Mt + (size_t)bh * 4096 + (size_t)(32 + j) * 64 + d8;
  short* oc = Mf + (size_t)b * 65536 + (size_t)j * 1024 + h * 64 + d8;
  short* os = Mf + (size_t)b * 65536 + (size_t)(32 + j) * 1024 + h * 64 + d8;
#pragma unroll
  for (int c = 0; c < 8; ++c) {
    const float a = m0[c], bb = m1[c];
    oc[c] = f2bf(p * a + q * bb);
    os[c] = f2bf(q * a - p * bb);
  }
}

// ---------------- H[b][o][kap] += sum_k Wob[o][k] * Mf[b][kap][k], split-K=8
__global__ __launch_bounds__(256) void hgemm_kernel(
    const short* __restrict__ Wob, const short* __restrict__ Mf,
    float* __restrict__ H) {
  const int kc = blockIdx.x;
  const int o0 = blockIdx.y * 64;
  const int b = blockIdx.z;
  const int t = threadIdx.x;
  const int lane = t & 63;
  const int w = t >> 6;
  const int lrow = lane & 15;
  const int kg = (lane >> 4) * 8;
  const int orow = o0 + w * 16 + lrow;
  f32x4 acc[4] = {};
#pragma unroll
  for (int it = 0; it < 4; ++it) {
    const int kb = kc * 128 + it * 32 + kg;
    const bfx8 af = *(const bfx8*)(Wob + (size_t)orow * 1024 + kb);
#pragma unroll
    for (int j = 0; j < 4; ++j) {
      const bfx8 bf_ = *(const bfx8*)(Mf + (size_t)b * 65536 +
                                      (size_t)(j * 16 + lrow) * 1024 + kb);
      acc[j] = __builtin_amdgcn_mfma_f32_16x16x32_bf16(af, bf_, acc[j], 0, 0, 0);
    }
  }
  float* Hb = H + (size_t)b * 65536;
#pragma unroll
  for (int j = 0; j < 4; ++j) {
    const int kap = j * 16 + lrow;
#pragma unroll
    for (int rr = 0; rr < 4; ++rr) {
      const int o = o0 + w * 16 + (lane >> 4) * 4 + rr;
      atomicAdd(&Hb[(size_t)o * 64 + kap], acc[j][rr]);
    }
  }
}

// ---------------- out[b][t][o] = sum_kap Cb[t][kap]*H[b][o][kap] + bo[o] ------
__global__ __launch_bounds__(256) void ofinal_kernel(
    const short* __restrict__ Cb, const float* __restrict__ H,
    const float* __restrict__ bo, float* __restrict__ out) {
  const int col0 = blockIdx.x * 128;
  const int row0 = blockIdx.y * 128;
  const int b = blockIdx.z;
  float* C = out + (size_t)b * 2097152;
  const float* Hb = H + (size_t)b * 65536;
  const int t = threadIdx.x;
  const int lane = t & 63;
  const int wv = t >> 6;
  const int wm = (wv & 1) * 64, wn = (wv >> 1) * 64;
  const int lrow = lane & 15;
  const int kg = (lane >> 4) * 8;
  f32x4 acc[4][4] = {};
#pragma unroll
  for (int k0 = 0; k0 < 64; k0 += 32) {
    bfx8 af[4], bf_[4];
#pragma unroll
    for (int i = 0; i < 4; ++i)
      af[i] = *(const bfx8*)(Cb + (size_t)(row0 + wm + i * 16 + lrow) * 64 + k0 + kg);
#pragma unroll
    for (int j = 0; j < 4; ++j) {
      const float* hp = Hb + (size_t)(col0 + wn + j * 16 + lrow) * 64 + k0 + kg;
      const float4 h0 = *(const float4*)hp;
      const float4 h1 = *(const float4*)(hp + 4);
      bfx8 bb;
      bb[0] = f2bf(h0.x); bb[1] = f2bf(h0.y); bb[2] = f2bf(h0.z); bb[3] = f2bf(h0.w);
      bb[4] = f2bf(h1.x); bb[5] = f2bf(h1.y); bb[6] = f2bf(h1.z); bb[7] = f2bf(h1.w);
      bf_[j] = bb;
    }
#pragma unroll
    for (int i = 0; i < 4; ++i)
#pragma unroll
      for (int j = 0; j < 4; ++j)
        acc[i][j] = __builtin_amdgcn_mfma_f32_16x16x32_bf16(af[i], bf_[j], acc[i][j], 0, 0, 0);
  }
  const int rq = (lane >> 4) * 4;
#pragma unroll
  for (int j = 0; j < 4; ++j) {
    const int c = col0 + wn + j * 16 + lrow;
    const float bb = bo[c];
#pragma unroll
    for (int i = 0; i < 4; ++i) {
      const int r = row0 + wm + i * 16 + rq;
#pragma unroll
      for (int rr = 0; rr < 4; ++rr)
        C[(size_t)(r + rr) * 1024 + c] = acc[i][j][rr] + bb;
    }
  }
}

extern "C" void kernel_launch(void* const* d_in, const int* in_sizes, int n_in,
                              void* d_out, int out_size, void* d_ws, size_t ws_size,
                              hipStream_t stream) {
  (void)in_sizes; (void)n_in; (void)out_size; (void)ws_size;
  const float* states = (const float*)d_in[0];
  const int* mask = (const int*)d_in[1];
  const float* ln_w = (const float*)d_in[2];
  const float* angles = (const float*)d_in[3];
  const float* delta = (const float*)d_in[4];
  // d_in[5]=Wq, d_in[6]=q_bias provably unused (softmax row-sums are 1).
  const float* Wk = (const float*)d_in[7];
  const float* bk = (const float*)d_in[8];
  const float* Wv = (const float*)d_in[9];
  const float* bv = (const float*)d_in[10];
  const float* Wo = (const float*)d_in[11];
  const float* bo = (const float*)d_in[12];
  float* out = (float*)d_out;

  char* W = (char*)d_ws;
  short* xb  = (short*)(W);                        // 8 MB   [4096][1024]
  short* Wkb = (short*)(W + (8u << 20));           // 2 MB
  short* Wvb = (short*)(W + (10u << 20));          // 2 MB
  short* Wob = (short*)(W + (12u << 20));          // 2 MB
  short* Cb  = (short*)(W + (14u << 20));          // 256 KB [2048][64]
  short* tkT = (short*)(W + (14u << 20) + (256u << 10));  // 256 KB [64][2048]
  short* Mf  = (short*)(W + (14u << 20) + (512u << 10));  // 256 KB [2][64][1024]
  float* Mt  = (float*)(W + (15u << 20));          // 512 KB [32][64][64]
  float* H   = (float*)(W + (15u << 20) + (512u << 10));  // 512 KB [2][1024][64]

  prep_kernel<<<7712, 256, 0, stream>>>(Wk, Wv, Wo, angles, states, ln_w,
                                        Wkb, Wvb, Wob, xb, Cb, tkT, Mt);
  kvgemm_kernel<<<dim3(32, 16), 256, 0, stream>>>(xb, Wkb, Wvb, bk, bv, mask,
                                                  tkT, Mt);
  fold_kernel<<<32, 256, 0, stream>>>(Mt, angles, delta, Mf);
  hgemm_kernel<<<dim3(8, 16, 2), 256, 0, stream>>>(Wob, Mf, H);
  ofinal_kernel<<<dim3(8, 16, 2), 256, 0, stream>>>(Cb, H, bo, out);
}